// Round 3
// baseline (808.490 us; speedup 1.0000x reference)
//
#include <hip/hip_runtime.h>

#define EMB 128
#define NBUC 1024          // coarse buckets: dst >> 7 (128 nodes per bucket)
#define NPART 256          // partition blocks for P1/P2
#define NSEG 8             // partition segments for the offset scan
#define SEGLEN (NPART / NSEG)   // 32
#define NSLOT 8            // dim-slices of 16 dims, one per XCD
#define GCH 128            // gather chunk: nodes per work item

typedef __attribute__((ext_vector_type(8))) short short8;   // 8 bf16 (4 VGPRs)
typedef __attribute__((ext_vector_type(4))) float f32x4;    // MFMA acc

// ---------------- bf16 helpers ----------------
__device__ __forceinline__ unsigned short f2bf(float f) {
    union { float f; unsigned int i; } v; v.f = f;
    unsigned int x = v.i;
    x += 0x7fffu + ((x >> 16) & 1u);   // round-to-nearest-even
    return (unsigned short)(x >> 16);
}
__device__ __forceinline__ void acc_bf2(unsigned int v, float& a0, float& a1) {
    union { unsigned int i; float f; } t;
    t.i = v << 16;          a0 += t.f;
    t.i = v & 0xffff0000u;  a1 += t.f;
}

// ============ CSR build: atomic-light two-level counting sort ============

__global__ __launch_bounds__(256) void p1_hist(const int* __restrict__ dst,
                                               int* __restrict__ BH, int E, int chunk) {
    __shared__ int h[NBUC];
    for (int i = threadIdx.x; i < NBUC; i += 256) h[i] = 0;
    __syncthreads();
    int s = blockIdx.x * chunk;
    int e = min(E, s + chunk);
    for (int i = s + threadIdx.x; i < e; i += 256)
        atomicAdd(&h[dst[i] >> 7], 1);
    __syncthreads();
    for (int i = threadIdx.x; i < NBUC; i += 256)
        BH[blockIdx.x * NBUC + i] = h[i];
}

// SS[seg][bucket] = sum of BH over the 32 partitions of that segment.
__global__ __launch_bounds__(256) void p_segsum(const int* __restrict__ BH,
                                                int* __restrict__ SS) {
    int idx = blockIdx.x * 256 + threadIdx.x;   // 0..8191
    int seg = idx >> 10, b = idx & (NBUC - 1);
    int s = 0;
#pragma unroll 8
    for (int k = 0; k < SEGLEN; ++k)
        s += BH[(seg * SEGLEN + k) * NBUC + b];
    SS[seg * NBUC + b] = s;
}

// Exclusive scan over bucket totals (totals folded in from SS: 8 loads/thread).
__global__ __launch_bounds__(1024) void p_scan(const int* __restrict__ SS,
                                               int* __restrict__ base, int E) {
    __shared__ int a[NBUC];
    int t = threadIdx.x;
    int v0 = 0;
#pragma unroll 8
    for (int s = 0; s < NSEG; ++s) v0 += SS[s * NBUC + t];
    a[t] = v0;
    __syncthreads();
    for (int off = 1; off < NBUC; off <<= 1) {
        int v = (t >= off) ? a[t - off] : 0;
        __syncthreads();
        a[t] += v;
        __syncthreads();
    }
    base[t] = a[t] - v0;
    if (t == NBUC - 1) base[NBUC] = E;
}

// BH[blk][b] <- base[b] + exclusive running sum over partitions < blk.
__global__ __launch_bounds__(256) void p_offs2(int* __restrict__ BH,
                                               const int* __restrict__ SS,
                                               const int* __restrict__ base) {
    int idx = blockIdx.x * 256 + threadIdx.x;   // 0..8191
    int seg = idx >> 10, b = idx & (NBUC - 1);
    int run = base[b];
    for (int s = 0; s < seg; ++s) run += SS[s * NBUC + b];
#pragma unroll 4
    for (int k = 0; k < SEGLEN; ++k) {
        int* p = &BH[(seg * SEGLEN + k) * NBUC + b];
        int v = *p;
        *p = run;
        run += v;
    }
}

__global__ __launch_bounds__(256) void p2_scatter(const int* __restrict__ src,
                                                  const int* __restrict__ dst,
                                                  const int* __restrict__ BH,
                                                  int* __restrict__ part,
                                                  int E, int chunk) {
    __shared__ int cnt[NBUC];
    for (int i = threadIdx.x; i < NBUC; i += 256)
        cnt[i] = BH[blockIdx.x * NBUC + i];
    __syncthreads();
    int s = blockIdx.x * chunk;
    int e = min(E, s + chunk);
    for (int i = s + threadIdx.x; i < e; i += 256) {
        int d = dst[i];
        int pos = atomicAdd(&cnt[d >> 7], 1);
        part[pos] = src[i] | ((d & 127) << 17);   // src < 2^17, local node in [0,128)
    }
}

__global__ __launch_bounds__(256) void p3_csr(const int* __restrict__ part,
                                              const int* __restrict__ base,
                                              int* __restrict__ R, int* __restrict__ adj,
                                              float* __restrict__ dis, int N, int E) {
    __shared__ int hist[128];
    __shared__ int sc[128];
    __shared__ int cnt[128];
    int b = blockIdx.x;
    int n0 = b * 128;
    int nn = min(128, N - n0);
    int s = base[b], e = base[b + 1];
    int t = threadIdx.x;

    if (t < 128) hist[t] = 0;
    __syncthreads();
    for (int i = s + t; i < e; i += 256)
        atomicAdd(&hist[part[i] >> 17], 1);
    __syncthreads();

    if (t < 128) sc[t] = hist[t];
    __syncthreads();
    for (int off = 1; off < 128; off <<= 1) {
        int v = 0;
        if (t < 128 && t >= off) v = sc[t - off];
        __syncthreads();
        if (t < 128) sc[t] += v;
        __syncthreads();
    }
    if (t < 128) {
        int excl = sc[t] - hist[t];
        cnt[t] = excl;
        if (t < nn) {
            R[n0 + t] = s + excl;
            dis[n0 + t] = rsqrtf((float)hist[t] + 1.0f);   // +1 self-loop
        }
    }
    if (b == 0 && t == 0) R[N] = E;
    __syncthreads();

    for (int i = s + t; i < e; i += 256) {
        int p = part[i];
        int pos = atomicAdd(&cnt[p >> 17], 1);
        adj[s + pos] = p & 0x1FFFF;
    }
}

// ---------------- W pre-swizzle: f32 [128][128] -> bf16 fragment order ----------------
// Both weight matrices in one launch; block 0 also zeroes the gather work counters.
__global__ __launch_bounds__(256) void k_prep_w2(const float* __restrict__ W1,
                                                 const float* __restrict__ W2,
                                                 unsigned short* __restrict__ W1s,
                                                 unsigned short* __restrict__ W2s,
                                                 int* __restrict__ ctr) {
    int gid = blockIdx.x * 256 + threadIdx.x;     // 128 blocks x 256 = 32768
    if (blockIdx.x == 0 && threadIdx.x < 2 * NSLOT) ctr[threadIdx.x] = 0;
    const float* W = (gid < 16384) ? W1 : W2;
    unsigned short* Ws = (gid < 16384) ? W1s : W2s;
    int idx = gid & 16383;
    int k = idx >> 7, n = idx & 127;
    int kk = k >> 5, q = (k >> 3) & 3, j = k & 7;
    int ct = n >> 4, nn = n & 15;
    int didx = ((((kk * 8 + ct) * 4 + q) * 16 + nn) << 3) + j;
    Ws[didx] = f2bf(W[idx]);
}

// ---------------- MFMA GEMM: Yb = bf16((X @ W) * dis), SLOT-BLOCKED output ----------
// Output layout: Yb[slot][node][16] bf16, slot = dim/16 (3.2MB per slot -> one
// XCD's L2).  64 nodes/block, 16/wave; K=128 as 4x mfma_f32_16x16x32_bf16.
// Fragment maps (doc-verified): A: m=lane&15, k=q*8+j; B: n=lane&15, k=q*8+j;
// D: n=lane&15, m=q*4+reg.  In-place safe for layer 2 (block touches only its
// own 64 rows; A-frag reads precede the store-side __syncthreads()).
template <bool XBF16>   // true: X is slot-blocked bf16; false: X is row-major f32
__global__ __launch_bounds__(256) void k_gemm_mfma(
    const void* Xv, const unsigned short* __restrict__ Wsw,
    const float* __restrict__ dis, unsigned short* Y, int N)
{
    __shared__ __align__(16) unsigned short lds[16384];   // 32 KB: W frags, then out-stage

    {
        const uint4* srcp = (const uint4*)Wsw;
        uint4* dstp = (uint4*)lds;
        for (int i = threadIdx.x; i < 2048; i += 256) dstp[i] = srcp[i];
    }
    __syncthreads();

    const int wave = threadIdx.x >> 6;
    const int lane = threadIdx.x & 63;
    const int q = lane >> 4, nn = lane & 15;
    const int row0 = blockIdx.x * 64 + wave * 16;
    const int arow = row0 + nn;
    const int arc = arow < N ? arow : N - 1;

    f32x4 acc[8];
#pragma unroll
    for (int ct = 0; ct < 8; ++ct) acc[ct] = (f32x4){0.f, 0.f, 0.f, 0.f};

#pragma unroll
    for (int kk = 0; kk < 4; ++kk) {
        short8 af;
        if (XBF16) {
            // dims kk*32 + q*8 .. +8  ->  slot = kk*2 + (q>>1), offset (q&1)*8
            const int slot = kk * 2 + (q >> 1);
            const int off = (q & 1) * 8;
            af = *(const short8*)((const unsigned short*)Xv +
                                  ((size_t)slot * N + arc) * 16 + off);
        } else {
            const float* xp = (const float*)Xv + (size_t)arc * EMB + kk * 32 + q * 8;
            float4 u0 = *(const float4*)xp;
            float4 u1 = *(const float4*)(xp + 4);
            af[0] = (short)f2bf(u0.x); af[1] = (short)f2bf(u0.y);
            af[2] = (short)f2bf(u0.z); af[3] = (short)f2bf(u0.w);
            af[4] = (short)f2bf(u1.x); af[5] = (short)f2bf(u1.y);
            af[6] = (short)f2bf(u1.z); af[7] = (short)f2bf(u1.w);
        }
#pragma unroll
        for (int ct = 0; ct < 8; ++ct) {
            short8 bf = ((const short8*)lds)[(kk * 8 + ct) * 64 + lane];
            acc[ct] = __builtin_amdgcn_mfma_f32_16x16x32_bf16(af, bf, acc[ct], 0, 0, 0);
        }
    }

    __syncthreads();   // W reads + all A-frag (X) reads complete block-wide

    float dv[4];
#pragma unroll
    for (int r = 0; r < 4; ++r) {
        int gm = row0 + q * 4 + r;
        dv[r] = dis[gm < N ? gm : N - 1];
    }
#pragma unroll
    for (int ct = 0; ct < 8; ++ct) {
#pragma unroll
        for (int r = 0; r < 4; ++r) {
            int ml = wave * 16 + q * 4 + r;
            lds[ml * 136 + ct * 16 + nn] = f2bf(acc[ct][r] * dv[r]);
        }
    }
    __syncthreads();

    // blocked store: per slot, 64 consecutive node-slices = 2KB contiguous
    const int rbase = blockIdx.x * 64;
    for (int i = threadIdx.x; i < 1024; i += 256) {
        int slot = i >> 7, r2 = (i >> 1) & 63, off = (i & 1) * 8;
        int grow = rbase + r2;
        if (grow < N) {
            uint4 v = *(const uint4*)(lds + r2 * 136 + slot * 16 + off);
            *(uint4*)(Y + ((size_t)slot * N + grow) * 16 + off) = v;
        }
    }
}

// ------------- gather + normalize + bias (+relu), XCD-PINNED dim-sharding -------------
// Each block reads its physical XCD id (HW_REG_XCC_ID, measured-valid on gfx950)
// and drains a per-slot atomic chunk counter for THAT slot's 3.2MB dim-slice,
// which therefore stays resident in the local 4MB L2.  After its own slot is
// drained it steals from the others (correctness independent of the XCD map).
// Layout: 8 dim-lanes/node x 4B = one contiguous 32B request per edge; stores
// fully coalesced.  Work per slot is identical -> perfectly balanced.
template <bool RELU, bool BF16OUT>
__global__ __launch_bounds__(256) void k_gather_xcd(
    const int* __restrict__ R, const int* __restrict__ adj,
    const unsigned short* __restrict__ Yb, const float* __restrict__ dis,
    const float* __restrict__ bias, void* __restrict__ Outv,
    int* __restrict__ ctr, int N)
{
    __shared__ int scur;
    int xcc;
    asm volatile("s_getreg_b32 %0, hwreg(HW_REG_XCC_ID)" : "=s"(xcc));
    xcc &= (NSLOT - 1);
    const int g = threadIdx.x >> 3;     // node group 0..31
    const int l = threadIdx.x & 7;      // dim lane: covers dims 2l, 2l+1 of the slot
    const int NCH = (N + GCH - 1) / GCH;

    for (int soff = 0; soff < NSLOT; ++soff) {
        const int slot = (xcc + soff) & (NSLOT - 1);
        const unsigned int* __restrict__ Ysu =
            (const unsigned int*)(Yb + (size_t)slot * N * 16);
        const float bl0 = bias[slot * 16 + l * 2];
        const float bl1 = bias[slot * 16 + l * 2 + 1];
        for (;;) {
            if (threadIdx.x == 0) scur = atomicAdd(&ctr[slot], 1);
            __syncthreads();
            const int c = scur;
            __syncthreads();
            if (c >= NCH) break;
            const int n0 = c * GCH;
#pragma unroll
            for (int p = 0; p < GCH / 32; ++p) {
                const int n = n0 + p * 32 + g;
                if (n >= N) continue;
                float a0, a1;
                {   // self term (rows already carry dis[src] from the GEMM)
                    unsigned int v = Ysu[n * 8 + l];
                    union { unsigned int i; float f; } t;
                    t.i = v << 16;         a0 = t.f;
                    t.i = v & 0xffff0000u; a1 = t.f;
                }
                int e = R[n];
                const int re = R[n + 1];
                for (; e + 3 < re; e += 4) {
                    int s0 = adj[e], s1 = adj[e + 1], s2 = adj[e + 2], s3 = adj[e + 3];
                    unsigned int v0 = Ysu[s0 * 8 + l];
                    unsigned int v1 = Ysu[s1 * 8 + l];
                    unsigned int v2 = Ysu[s2 * 8 + l];
                    unsigned int v3 = Ysu[s3 * 8 + l];
                    acc_bf2(v0, a0, a1); acc_bf2(v1, a0, a1);
                    acc_bf2(v2, a0, a1); acc_bf2(v3, a0, a1);
                }
                for (; e < re; ++e) {
                    acc_bf2(Ysu[adj[e] * 8 + l], a0, a1);
                }
                const float dv = dis[n];
                float o0 = dv * a0 + bl0;
                float o1 = dv * a1 + bl1;
                if (RELU) { o0 = fmaxf(o0, 0.f); o1 = fmaxf(o1, 0.f); }
                if (BF16OUT) {
                    // slot-blocked bf16 (feeds layer-2 GEMM)
                    unsigned int pk = (unsigned)f2bf(o0) | ((unsigned)f2bf(o1) << 16);
                    ((unsigned int*)Outv)[(size_t)slot * N * 8 + n * 8 + l] = pk;
                } else {
                    // final output: row-major f32 (64B contiguous per node-slot)
                    float2 o = { o0, o1 };
                    *(float2*)((float*)Outv + (size_t)n * EMB + slot * 16 + l * 2) = o;
                }
            }
        }
    }
}

extern "C" void kernel_launch(void* const* d_in, const int* in_sizes, int n_in,
                              void* d_out, int out_size, void* d_ws, size_t ws_size,
                              hipStream_t stream) {
    const int* ei = (const int*)d_in[0];
    const int E = in_sizes[0] / 2;
    const float* emb = (const float*)d_in[2];
    const int N = in_sizes[2] / EMB;
    const float* W1 = (const float*)d_in[3];
    const float* b1 = (const float*)d_in[4];
    const float* W2 = (const float*)d_in[5];
    const float* b2 = (const float*)d_in[6];
    float* out = (float*)d_out;

    const int* src = ei;
    const int* dstp = ei + E;

    // ws: dis | R | base | SS | ctr | adj | W1s | W2s | Hb (part/BH overlay Hb).
    // Y1b lives in d_out bytes (dead before gather2 writes d_out f32).
    char* w = (char*)d_ws;
    auto take = [&](size_t bytes) { char* p = w; w += (bytes + 511) & ~(size_t)511; return p; };
    float* dis  = (float*)take((size_t)N * 4);
    int*   R    = (int*)  take((size_t)(N + 1) * 4);
    int*   base = (int*)  take((size_t)(NBUC + 1) * 4);
    int*   SS   = (int*)  take((size_t)NSEG * NBUC * 4);
    int*   ctr  = (int*)  take((size_t)2 * NSLOT * 4);
    int*   adj  = (int*)  take((size_t)E * 4);
    unsigned short* W1s = (unsigned short*)take((size_t)EMB * EMB * 2);
    unsigned short* W2s = (unsigned short*)take((size_t)EMB * EMB * 2);
    unsigned short* Hb  = (unsigned short*)take((size_t)N * EMB * 2);
    int*   part = (int*)Hb;                                  // overlay (dead before Hb)
    int*   BH   = (int*)((char*)Hb + (((size_t)E * 4 + 511) & ~(size_t)511));
    unsigned short* Y1b = (unsigned short*)d_out;            // overlay in d_out

    const int NB = (N + 127) / 128;
    const int chunk = (E + NPART - 1) / NPART;
    const int gM = (N + 63) / 64;            // MFMA gemm blocks
    const int gG = 2048;                     // persistent-ish gather blocks (8/CU)
    const int gS = (NSEG * NBUC) / 256;      // 32 blocks for segsum/offs

    // --- CSR + dis build (shared by both layers) ---
    p1_hist   <<<NPART, 256, 0, stream>>>(dstp, BH, E, chunk);
    p_segsum  <<<gS, 256, 0, stream>>>(BH, SS);
    p_scan    <<<1, NBUC, 0, stream>>>(SS, base, E);
    p_offs2   <<<gS, 256, 0, stream>>>(BH, SS, base);
    p2_scatter<<<NPART, 256, 0, stream>>>(src, dstp, BH, part, E, chunk);
    p3_csr    <<<NB, 256, 0, stream>>>(part, base, R, adj, dis, N, E);

    // --- weight pre-swizzle (both W) + zero gather counters ---
    k_prep_w2<<<128, 256, 0, stream>>>(W1, W2, W1s, W2s, ctr);

    // --- layer 1: Y1b = bf16((emb@W1)*dis) blocked; Hb = bf16(relu(...)) blocked ---
    k_gemm_mfma<false><<<gM, 256, 0, stream>>>(emb, W1s, dis, Y1b, N);
    k_gather_xcd<true, true><<<gG, 256, 0, stream>>>(R, adj, Y1b, dis, b1, Hb, ctr, N);

    // --- layer 2: Hb = bf16((Hb@W2)*dis) in-place blocked; out = f32 rows ---
    k_gemm_mfma<true><<<gM, 256, 0, stream>>>(Hb, W2s, dis, Hb, N);
    k_gather_xcd<false, false><<<gG, 256, 0, stream>>>(R, adj, Hb, dis, b2, out, ctr + NSLOT, N);
}

// Round 5
// 327.653 us; speedup vs baseline: 2.4675x; 2.4675x over previous
//
#include <hip/hip_runtime.h>

#define EMB 128
#define NBUC 1024          // coarse buckets: dst >> 7 (128 nodes per bucket)
#define NPART 256          // partition blocks for P1/P2
#define NSEG 8             // partition segments for the offset scan
#define SEGLEN (NPART / NSEG)   // 32
#define PREPB 128          // prep_w blocks appended to k_start

typedef __attribute__((ext_vector_type(8))) short short8;   // 8 bf16 (4 VGPRs)
typedef __attribute__((ext_vector_type(4))) float f32x4;    // MFMA acc

// ---------------- bf16 helpers ----------------
__device__ __forceinline__ unsigned short f2bf(float f) {
    union { float f; unsigned int i; } v; v.f = f;
    unsigned int x = v.i;
    x += 0x7fffu + ((x >> 16) & 1u);   // round-to-nearest-even
    return (unsigned short)(x >> 16);
}
// a += d * unpack_bf16x4(v)   (4 fma; same VALU count as the plain add version)
__device__ __forceinline__ void acc_fma4(uint2 v, float d,
                                         float& a0, float& a1, float& a2, float& a3) {
    union { unsigned int i; float f; } t;
    t.i = v.x << 16;          a0 = fmaf(d, t.f, a0);
    t.i = v.x & 0xffff0000u;  a1 = fmaf(d, t.f, a1);
    t.i = v.y << 16;          a2 = fmaf(d, t.f, a2);
    t.i = v.y & 0xffff0000u;  a3 = fmaf(d, t.f, a3);
}

// ============ CSR build: atomic-light two-level counting sort ============

__device__ __forceinline__ void p1_body(int bid, int* h, const int* __restrict__ dst,
                                        int* __restrict__ BH, int E, int chunk) {
    for (int i = threadIdx.x; i < NBUC; i += 256) h[i] = 0;
    __syncthreads();
    int s = bid * chunk;
    int e = min(E, s + chunk);
    for (int i = s + threadIdx.x; i < e; i += 256)
        atomicAdd(&h[dst[i] >> 7], 1);
    __syncthreads();
    for (int i = threadIdx.x; i < NBUC; i += 256)
        BH[bid * NBUC + i] = h[i];
}

// W pre-swizzle: f32 [128][128] -> bf16 fragment order.
// Wb[kk][ct][q][nn][j] = W[kk*32+q*8+j][ct*16+nn]; lane (q*16+nn) reads its B-frag
// for (kk,ct) as one contiguous 16B short8 at index (kk*8+ct)*64 + lane.
__device__ __forceinline__ void prepw_body(int bid, const float* __restrict__ W1,
                                           const float* __restrict__ W2,
                                           unsigned short* __restrict__ W1s,
                                           unsigned short* __restrict__ W2s) {
    int gid = bid * 256 + threadIdx.x;            // 128 blocks x 256 = 32768
    const float* W = (gid < 16384) ? W1 : W2;
    unsigned short* Ws = (gid < 16384) ? W1s : W2s;
    int idx = gid & 16383;
    int k = idx >> 7, n = idx & 127;
    int kk = k >> 5, q = (k >> 3) & 3, j = k & 7;
    int ct = n >> 4, nn = n & 15;
    int didx = ((((kk * 8 + ct) * 4 + q) * 16 + nn) << 3) + j;
    Ws[didx] = f2bf(W[idx]);
}

// K1: blocks [0,NPART) = p1_hist; [NPART, NPART+PREPB) = weight pre-swizzle.
__global__ __launch_bounds__(256) void k_start(const int* __restrict__ dst,
                                               int* __restrict__ BH, int E, int chunk,
                                               const float* __restrict__ W1,
                                               const float* __restrict__ W2,
                                               unsigned short* __restrict__ W1s,
                                               unsigned short* __restrict__ W2s) {
    __shared__ int h[NBUC];
    int b = blockIdx.x;
    if (b < NPART) p1_body(b, h, dst, BH, E, chunk);
    else           prepw_body(b - NPART, W1, W2, W1s, W2s);
}

// SS[seg][bucket] = sum of BH over the 32 partitions of that segment.
__global__ __launch_bounds__(256) void p_segsum(const int* __restrict__ BH,
                                                int* __restrict__ SS) {
    int idx = blockIdx.x * 256 + threadIdx.x;   // 0..8191
    int seg = idx >> 10, b = idx & (NBUC - 1);
    int s = 0;
#pragma unroll 8
    for (int k = 0; k < SEGLEN; ++k)
        s += BH[(seg * SEGLEN + k) * NBUC + b];
    SS[seg * NBUC + b] = s;
}

// Exclusive scan over bucket totals (totals folded in from SS: 8 loads/thread).
__global__ __launch_bounds__(1024) void p_scan(const int* __restrict__ SS,
                                               int* __restrict__ base, int E) {
    __shared__ int a[NBUC];
    int t = threadIdx.x;
    int v0 = 0;
#pragma unroll 8
    for (int s = 0; s < NSEG; ++s) v0 += SS[s * NBUC + t];
    a[t] = v0;
    __syncthreads();
    for (int off = 1; off < NBUC; off <<= 1) {
        int v = (t >= off) ? a[t - off] : 0;
        __syncthreads();
        a[t] += v;
        __syncthreads();
    }
    base[t] = a[t] - v0;
    if (t == NBUC - 1) base[NBUC] = E;
}

// BH[blk][b] <- base[b] + exclusive running sum over partitions < blk.
__global__ __launch_bounds__(256) void p_offs2(int* __restrict__ BH,
                                               const int* __restrict__ SS,
                                               const int* __restrict__ base) {
    int idx = blockIdx.x * 256 + threadIdx.x;   // 0..8191
    int seg = idx >> 10, b = idx & (NBUC - 1);
    int run = base[b];
    for (int s = 0; s < seg; ++s) run += SS[s * NBUC + b];
#pragma unroll 4
    for (int k = 0; k < SEGLEN; ++k) {
        int* p = &BH[(seg * SEGLEN + k) * NBUC + b];
        int v = *p;
        *p = run;
        run += v;
    }
}

__device__ __forceinline__ void scatter_body(int bid, int* cnt,
                                             const int* __restrict__ src,
                                             const int* __restrict__ dst,
                                             const int* __restrict__ BH,
                                             int* __restrict__ part,
                                             int E, int chunk) {
    for (int i = threadIdx.x; i < NBUC; i += 256)
        cnt[i] = BH[bid * NBUC + i];
    __syncthreads();
    int s = bid * chunk;
    int e = min(E, s + chunk);
    for (int i = s + threadIdx.x; i < e; i += 256) {
        int d = dst[i];
        int pos = atomicAdd(&cnt[d >> 7], 1);
        part[pos] = src[i] | ((d & 127) << 17);   // src < 2^17, local node in [0,128)
    }
}

__global__ __launch_bounds__(256) void p3_csr(const int* __restrict__ part,
                                              const int* __restrict__ base,
                                              int* __restrict__ R, int* __restrict__ adj,
                                              float* __restrict__ dis, int N, int E) {
    __shared__ int hist[128];
    __shared__ int sc[128];
    __shared__ int cnt[128];
    int b = blockIdx.x;
    int n0 = b * 128;
    int nn = min(128, N - n0);
    int s = base[b], e = base[b + 1];
    int t = threadIdx.x;

    if (t < 128) hist[t] = 0;
    __syncthreads();
    for (int i = s + t; i < e; i += 256)
        atomicAdd(&hist[part[i] >> 17], 1);
    __syncthreads();

    if (t < 128) sc[t] = hist[t];
    __syncthreads();
    for (int off = 1; off < 128; off <<= 1) {
        int v = 0;
        if (t < 128 && t >= off) v = sc[t - off];
        __syncthreads();
        if (t < 128) sc[t] += v;
        __syncthreads();
    }
    if (t < 128) {
        int excl = sc[t] - hist[t];
        cnt[t] = excl;
        if (t < nn) {
            R[n0 + t] = s + excl;
            dis[n0 + t] = rsqrtf((float)hist[t] + 1.0f);   // +1 self-loop
        }
    }
    if (b == 0 && t == 0) R[N] = E;
    __syncthreads();

    for (int i = s + t; i < e; i += 256) {
        int p = part[i];
        int pos = atomicAdd(&cnt[p >> 17], 1);
        adj[s + pos] = p & 0x1FFFF;
    }
}

// ---------------- MFMA GEMM body: Y[n] = bf16(X[n] @ W), UNSCALED ----------------
// 64 nodes/block, 16/wave; K=128 as 4 steps of mfma_f32_16x16x32_bf16.
// Fragment maps (doc-verified): A: m=lane&15, k=q*8+j; B: n=lane&15, k=q*8+j;
// D: n=lane&15, m=q*4+reg.  dis normalization is folded into the gather
// (breaks the gemm1->CSR dependency so gemm1 merges with p2_scatter).
// In-place safe (X==Y): a block touches only its own 64 rows; all A-frag reads
// happen before the store-side __syncthreads().
template <bool XBF16>
__device__ __forceinline__ void gemm_body(int bid, unsigned short* lds,
    const void* Xv, const unsigned short* __restrict__ Wsw,
    unsigned short* __restrict__ Y, int N)
{
    // stage swizzled W (coalesced 16B copies)
    {
        const uint4* srcp = (const uint4*)Wsw;
        uint4* dstp = (uint4*)lds;
        for (int i = threadIdx.x; i < 2048; i += 256) dstp[i] = srcp[i];
    }
    __syncthreads();

    const int wave = threadIdx.x >> 6;
    const int lane = threadIdx.x & 63;
    const int q = lane >> 4, nn = lane & 15;
    const int row0 = bid * 64 + wave * 16;
    const int arow = row0 + nn;
    const int arc = arow < N ? arow : N - 1;

    f32x4 acc[8];
#pragma unroll
    for (int ct = 0; ct < 8; ++ct) acc[ct] = (f32x4){0.f, 0.f, 0.f, 0.f};

#pragma unroll
    for (int kk = 0; kk < 4; ++kk) {
        short8 af;
        if (XBF16) {
            af = *(const short8*)((const unsigned short*)Xv + (size_t)arc * EMB + kk * 32 + q * 8);
        } else {
            const float* xp = (const float*)Xv + (size_t)arc * EMB + kk * 32 + q * 8;
            float4 u0 = *(const float4*)xp;
            float4 u1 = *(const float4*)(xp + 4);
            af[0] = (short)f2bf(u0.x); af[1] = (short)f2bf(u0.y);
            af[2] = (short)f2bf(u0.z); af[3] = (short)f2bf(u0.w);
            af[4] = (short)f2bf(u1.x); af[5] = (short)f2bf(u1.y);
            af[6] = (short)f2bf(u1.z); af[7] = (short)f2bf(u1.w);
        }
#pragma unroll
        for (int ct = 0; ct < 8; ++ct) {
            short8 bf = ((const short8*)lds)[(kk * 8 + ct) * 64 + lane];
            acc[ct] = __builtin_amdgcn_mfma_f32_16x16x32_bf16(af, bf, acc[ct], 0, 0, 0);
        }
    }

    __syncthreads();   // W reads + all A-frag (X) reads complete block-wide

    // pack bf16, stage to LDS (stride 136 shorts = 272B, 16B-aligned)
#pragma unroll
    for (int ct = 0; ct < 8; ++ct) {
#pragma unroll
        for (int r = 0; r < 4; ++r) {
            int ml = wave * 16 + q * 4 + r;
            lds[ml * 136 + ct * 16 + nn] = f2bf(acc[ct][r]);
        }
    }
    __syncthreads();

    // coalesced store: 64 rows x 256B, 16B per thread-item
    const int rbase = bid * 64;
    for (int i = threadIdx.x; i < 1024; i += 256) {
        int row = i >> 4, off = i & 15;
        int grow = rbase + row;
        if (grow < N) {
            uint4 v = *(const uint4*)(lds + row * 136 + off * 8);
            *((uint4*)(Y + (size_t)grow * EMB) + off) = v;
        }
    }
}

// K5: blocks [0,NPART) = p2_scatter; [NPART, NPART+gM) = layer-1 GEMM (f32 input).
__global__ __launch_bounds__(256) void k_mid(
    const int* __restrict__ src, const int* __restrict__ dstp,
    const int* __restrict__ BH, int* __restrict__ part, int E, int chunk,
    const void* Xv, const unsigned short* __restrict__ W1s,
    unsigned short* __restrict__ Y, int N)
{
    __shared__ __align__(16) unsigned short smem[16384];   // 32 KB (scatter uses 4 KB)
    int b = blockIdx.x;
    if (b < NPART) scatter_body(b, (int*)smem, src, dstp, BH, part, E, chunk);
    else           gemm_body<false>(b - NPART, smem, Xv, W1s, Y, N);
}

// Layer-2 GEMM (bf16 input, in-place).
__global__ __launch_bounds__(256) void k_gemm2(
    const void* Xv, const unsigned short* __restrict__ Wsw,
    unsigned short* __restrict__ Y, int N)
{
    __shared__ __align__(16) unsigned short smem[16384];
    gemm_body<true>(blockIdx.x, smem, Xv, Wsw, Y, N);
}

// ---------------- fused gather + symmetric-norm + bias (+relu) ----------------
// 32 threads/node: a wave's 64 lanes cover 2 nodes reading full contiguous
// 256-B rows (coalesced).  Y rows are UNSCALED; norm applied here:
//   out[n] = dis[n] * ( sum_s dis[s]*Y[s]  +  dis[n]*Y[n] ) + b
// dis is a 400 KB table -> L2-resident broadcast loads (32 lanes share address).
template <bool RELU, bool BF16OUT>
__global__ __launch_bounds__(256) void k_gather_finalize(
    const int* __restrict__ R, const int* __restrict__ adj,
    const unsigned short* __restrict__ Y, const float* __restrict__ dis,
    const float* __restrict__ bias, void* __restrict__ Outv, int N)
{
    int t = blockIdx.x * 256 + threadIdx.x;
    int n = t >> 5;
    if (n >= N) return;
    int j = (t & 31) * 4;

    int rs = R[n], re = R[n + 1];
    float dv = dis[n];

    float a0 = 0.f, a1 = 0.f, a2 = 0.f, a3 = 0.f;
    uint2 sv = *(const uint2*)(Y + (size_t)n * EMB + j);
    acc_fma4(sv, dv, a0, a1, a2, a3);        // self term: dv * Y[n]

    int e = rs;
    for (; e + 3 < re; e += 4) {
        int s0 = adj[e], s1 = adj[e + 1], s2 = adj[e + 2], s3 = adj[e + 3];
        float d0 = dis[s0], d1 = dis[s1], d2 = dis[s2], d3 = dis[s3];
        uint2 v0 = *(const uint2*)(Y + (size_t)s0 * EMB + j);
        uint2 v1 = *(const uint2*)(Y + (size_t)s1 * EMB + j);
        uint2 v2 = *(const uint2*)(Y + (size_t)s2 * EMB + j);
        uint2 v3 = *(const uint2*)(Y + (size_t)s3 * EMB + j);
        acc_fma4(v0, d0, a0, a1, a2, a3);
        acc_fma4(v1, d1, a0, a1, a2, a3);
        acc_fma4(v2, d2, a0, a1, a2, a3);
        acc_fma4(v3, d3, a0, a1, a2, a3);
    }
    for (; e < re; ++e) {
        int s0 = adj[e];
        float d0 = dis[s0];
        uint2 v0 = *(const uint2*)(Y + (size_t)s0 * EMB + j);
        acc_fma4(v0, d0, a0, a1, a2, a3);
    }

    float4 b = *(const float4*)(bias + j);
    float o0 = dv * a0 + b.x;
    float o1 = dv * a1 + b.y;
    float o2 = dv * a2 + b.z;
    float o3 = dv * a3 + b.w;
    if (RELU) {
        o0 = fmaxf(o0, 0.f); o1 = fmaxf(o1, 0.f);
        o2 = fmaxf(o2, 0.f); o3 = fmaxf(o3, 0.f);
    }
    if (BF16OUT) {
        ushort4 o = { f2bf(o0), f2bf(o1), f2bf(o2), f2bf(o3) };
        *(ushort4*)((unsigned short*)Outv + (size_t)n * EMB + j) = o;
    } else {
        float4 o = { o0, o1, o2, o3 };
        *(float4*)((float*)Outv + (size_t)n * EMB + j) = o;
    }
}

extern "C" void kernel_launch(void* const* d_in, const int* in_sizes, int n_in,
                              void* d_out, int out_size, void* d_ws, size_t ws_size,
                              hipStream_t stream) {
    const int* ei = (const int*)d_in[0];
    const int E = in_sizes[0] / 2;
    const float* emb = (const float*)d_in[2];
    const int N = in_sizes[2] / EMB;
    const float* W1 = (const float*)d_in[3];
    const float* b1 = (const float*)d_in[4];
    const float* W2 = (const float*)d_in[5];
    const float* b2 = (const float*)d_in[6];
    float* out = (float*)d_out;

    const int* src = ei;
    const int* dstp = ei + E;

    // ws: dis | R | base | SS | adj | W1s | W2s | Hb (part/BH overlay Hb; both
    // dead before gather1 writes Hb).  Y1b lives in d_out bytes (dead before
    // gather2 writes d_out f32).
    char* w = (char*)d_ws;
    auto take = [&](size_t bytes) { char* p = w; w += (bytes + 511) & ~(size_t)511; return p; };
    float* dis  = (float*)take((size_t)N * 4);
    int*   R    = (int*)  take((size_t)(N + 1) * 4);
    int*   base = (int*)  take((size_t)(NBUC + 1) * 4);
    int*   SS   = (int*)  take((size_t)NSEG * NBUC * 4);
    int*   adj  = (int*)  take((size_t)E * 4);
    unsigned short* W1s = (unsigned short*)take((size_t)EMB * EMB * 2);
    unsigned short* W2s = (unsigned short*)take((size_t)EMB * EMB * 2);
    unsigned short* Hb  = (unsigned short*)take((size_t)N * EMB * 2);
    int*   part = (int*)Hb;                                  // overlay (dead before Hb)
    int*   BH   = (int*)((char*)Hb + (((size_t)E * 4 + 511) & ~(size_t)511));
    unsigned short* Y1b = (unsigned short*)d_out;            // overlay in d_out

    const int NB = (N + 127) / 128;
    const int chunk = (E + NPART - 1) / NPART;
    const int gM = (N + 63) / 64;            // MFMA gemm blocks
    const int gG = (N * 32 + 255) / 256;     // gather blocks
    const int gS = (NSEG * NBUC) / 256;      // 32 blocks for segsum/offs

    // --- K1: edge histogram (CSR) in parallel with weight pre-swizzle ---
    k_start   <<<NPART + PREPB, 256, 0, stream>>>(dstp, BH, E, chunk, W1, W2, W1s, W2s);
    p_segsum  <<<gS, 256, 0, stream>>>(BH, SS);
    p_scan    <<<1, NBUC, 0, stream>>>(SS, base, E);
    p_offs2   <<<gS, 256, 0, stream>>>(BH, SS, base);

    // --- K5: edge scatter in parallel with layer-1 GEMM (unscaled Y1b) ---
    k_mid     <<<NPART + gM, 256, 0, stream>>>(src, dstp, BH, part, E, chunk,
                                               emb, W1s, Y1b, N);
    p3_csr    <<<NB, 256, 0, stream>>>(part, base, R, adj, dis, N, E);

    // --- layer 1 gather: Hb = bf16(relu(dis*(sum dis[s]*Y1b[s] + dis*Y1b[n]) + b1)) ---
    k_gather_finalize<true, true><<<gG, 256, 0, stream>>>(R, adj, Y1b, dis, b1, Hb, N);

    // --- layer 2: Hb = bf16(Hb@W2) in-place; out = dis*(sum+self) + b2 (f32) ---
    k_gemm2<<<gM, 256, 0, stream>>>(Hb, W2s, Hb, N);
    k_gather_finalize<false, false><<<gG, 256, 0, stream>>>(R, adj, Hb, dis, b2, out, N);
}

// Round 6
// 327.648 us; speedup vs baseline: 2.4676x; 1.0000x over previous
//
#include <hip/hip_runtime.h>

#define EMB 128
#define NBUC 1024          // coarse buckets: dst >> 7 (128 nodes per bucket)
#define NPART 256          // partition blocks for hist/scatter
#define PREPB 128          // prep_w blocks appended to k_start

typedef __attribute__((ext_vector_type(8))) short short8;   // 8 bf16 (4 VGPRs)
typedef __attribute__((ext_vector_type(4))) float f32x4;    // MFMA acc

// ---------------- bf16 helpers ----------------
__device__ __forceinline__ unsigned short f2bf(float f) {
    union { float f; unsigned int i; } v; v.f = f;
    unsigned int x = v.i;
    x += 0x7fffu + ((x >> 16) & 1u);   // round-to-nearest-even
    return (unsigned short)(x >> 16);
}
// a += d * unpack_bf16x4(v)
__device__ __forceinline__ void acc_fma4(uint2 v, float d,
                                         float& a0, float& a1, float& a2, float& a3) {
    union { unsigned int i; float f; } t;
    t.i = v.x << 16;          a0 = fmaf(d, t.f, a0);
    t.i = v.x & 0xffff0000u;  a1 = fmaf(d, t.f, a1);
    t.i = v.y << 16;          a2 = fmaf(d, t.f, a2);
    t.i = v.y & 0xffff0000u;  a3 = fmaf(d, t.f, a3);
}
// a += unpack_bf16x4(v)
__device__ __forceinline__ void acc_bf4(uint2 v,
                                        float& a0, float& a1, float& a2, float& a3) {
    union { unsigned int i; float f; } t;
    t.i = v.x << 16;          a0 += t.f;
    t.i = v.x & 0xffff0000u;  a1 += t.f;
    t.i = v.y << 16;          a2 += t.f;
    t.i = v.y & 0xffff0000u;  a3 += t.f;
}

// ============ CSR build: reservation counting sort (no BH matrix) ============

// hist chunk into LDS, then one global atomicAdd per nonzero bucket.
__device__ __forceinline__ void p1_body(int bid, int* h, const int* __restrict__ dst,
                                        int* __restrict__ tot, int E, int chunk) {
    for (int i = threadIdx.x; i < NBUC; i += 256) h[i] = 0;
    __syncthreads();
    int s = bid * chunk;
    int e = min(E, s + chunk);
    for (int i = s + threadIdx.x; i < e; i += 256)
        atomicAdd(&h[dst[i] >> 7], 1);
    __syncthreads();
    for (int i = threadIdx.x; i < NBUC; i += 256) {
        int v = h[i];
        if (v) atomicAdd(&tot[i], v);
    }
}

// W pre-swizzle: f32 [128][128] -> bf16 fragment order.
// Wb[kk][ct][q][nn][j] = W[kk*32+q*8+j][ct*16+nn]; lane (q*16+nn) reads its B-frag
// for (kk,ct) as one contiguous 16B short8 at index (kk*8+ct)*64 + lane.
__device__ __forceinline__ void prepw_body(int bid, const float* __restrict__ W1,
                                           const float* __restrict__ W2,
                                           unsigned short* __restrict__ W1s,
                                           unsigned short* __restrict__ W2s) {
    int gid = bid * 256 + threadIdx.x;            // 128 blocks x 256 = 32768
    const float* W = (gid < 16384) ? W1 : W2;
    unsigned short* Ws = (gid < 16384) ? W1s : W2s;
    int idx = gid & 16383;
    int k = idx >> 7, n = idx & 127;
    int kk = k >> 5, q = (k >> 3) & 3, j = k & 7;
    int ct = n >> 4, nn = n & 15;
    int didx = ((((kk * 8 + ct) * 4 + q) * 16 + nn) << 3) + j;
    Ws[didx] = f2bf(W[idx]);
}

// K1: blocks [0,NPART) = hist; [NPART, NPART+PREPB) = weight pre-swizzle.
__global__ __launch_bounds__(256) void k_start(const int* __restrict__ dst,
                                               int* __restrict__ tot, int E, int chunk,
                                               const float* __restrict__ W1,
                                               const float* __restrict__ W2,
                                               unsigned short* __restrict__ W1s,
                                               unsigned short* __restrict__ W2s) {
    __shared__ int h[NBUC];
    int b = blockIdx.x;
    if (b < NPART) p1_body(b, h, dst, tot, E, chunk);
    else           prepw_body(b - NPART, W1, W2, W1s, W2s);
}

// Exclusive scan of bucket totals -> base[]; also init the global cursors gcnt[].
__global__ __launch_bounds__(1024) void p_scan(const int* __restrict__ tot,
                                               int* __restrict__ base,
                                               int* __restrict__ gcnt, int E) {
    __shared__ int a[NBUC];
    int t = threadIdx.x;
    int v0 = tot[t];
    a[t] = v0;
    __syncthreads();
    for (int off = 1; off < NBUC; off <<= 1) {
        int v = (t >= off) ? a[t - off] : 0;
        __syncthreads();
        a[t] += v;
        __syncthreads();
    }
    int excl = a[t] - v0;
    base[t] = excl;
    gcnt[t] = excl;
    if (t == NBUC - 1) base[NBUC] = E;
}

// Reservation scatter: pass1 count chunk's buckets in LDS; reserve ranges via one
// global atomicAdd per (block,bucket); pass2 re-read chunk (L1/L2-hot) and place.
// Intra-bucket order is arbitrary (p3 re-sorts by node; sums are order-indep).
__device__ __forceinline__ void scatter_body(int bid, int* cnt,
                                             const int* __restrict__ src,
                                             const int* __restrict__ dst,
                                             int* __restrict__ gcnt,
                                             int* __restrict__ part,
                                             int E, int chunk) {
    for (int i = threadIdx.x; i < NBUC; i += 256) cnt[i] = 0;
    __syncthreads();
    int s = bid * chunk;
    int e = min(E, s + chunk);
    for (int i = s + threadIdx.x; i < e; i += 256)
        atomicAdd(&cnt[dst[i] >> 7], 1);
    __syncthreads();
    for (int i = threadIdx.x; i < NBUC; i += 256) {
        int c = cnt[i];
        cnt[i] = c ? atomicAdd(&gcnt[i], c) : 0;   // LDS cursor := global base
    }
    __syncthreads();
    for (int i = s + threadIdx.x; i < e; i += 256) {
        int d = dst[i];
        int pos = atomicAdd(&cnt[d >> 7], 1);
        part[pos] = src[i] | ((d & 127) << 17);    // src < 2^17, local node in [0,128)
    }
}

__global__ __launch_bounds__(256) void p3_csr(const int* __restrict__ part,
                                              const int* __restrict__ base,
                                              int* __restrict__ R, int* __restrict__ adj,
                                              float* __restrict__ dis, int N, int E) {
    __shared__ int hist[128];
    __shared__ int sc[128];
    __shared__ int cnt[128];
    int b = blockIdx.x;
    int n0 = b * 128;
    int nn = min(128, N - n0);
    int s = base[b], e = base[b + 1];
    int t = threadIdx.x;

    if (t < 128) hist[t] = 0;
    __syncthreads();
    for (int i = s + t; i < e; i += 256)
        atomicAdd(&hist[part[i] >> 17], 1);
    __syncthreads();

    if (t < 128) sc[t] = hist[t];
    __syncthreads();
    for (int off = 1; off < 128; off <<= 1) {
        int v = 0;
        if (t < 128 && t >= off) v = sc[t - off];
        __syncthreads();
        if (t < 128) sc[t] += v;
        __syncthreads();
    }
    if (t < 128) {
        int excl = sc[t] - hist[t];
        cnt[t] = excl;
        if (t < nn) {
            R[n0 + t] = s + excl;
            dis[n0 + t] = rsqrtf((float)hist[t] + 1.0f);   // +1 self-loop
        }
    }
    if (b == 0 && t == 0) R[N] = E;
    __syncthreads();

    for (int i = s + t; i < e; i += 256) {
        int p = part[i];
        int pos = atomicAdd(&cnt[p >> 17], 1);
        adj[s + pos] = p & 0x1FFFF;
    }
}

// ---------------- MFMA GEMM body: Y[n] = bf16((X[n] @ W) [* dis[n]]) ----------------
// 64 nodes/block, 16/wave; K=128 as 4 steps of mfma_f32_16x16x32_bf16.
// Fragment maps (doc-verified): A: m=lane&15, k=q*8+j; B: n=lane&15, k=q*8+j;
// D: n=lane&15, m=q*4+reg.  SCALE=false for layer 1 (dis not ready; norm folded
// into gather1); SCALE=true for layer 2 (dis ready -> gather2 needs no dis[s]).
// In-place safe (X==Y): a block touches only its own 64 rows; all A-frag reads
// happen before the store-side __syncthreads().
template <bool XBF16, bool SCALE>
__device__ __forceinline__ void gemm_body(int bid, unsigned short* lds,
    const void* Xv, const unsigned short* __restrict__ Wsw,
    const float* __restrict__ dis, unsigned short* __restrict__ Y, int N)
{
    // stage swizzled W (coalesced 16B copies)
    {
        const uint4* srcp = (const uint4*)Wsw;
        uint4* dstp = (uint4*)lds;
        for (int i = threadIdx.x; i < 2048; i += 256) dstp[i] = srcp[i];
    }
    __syncthreads();

    const int wave = threadIdx.x >> 6;
    const int lane = threadIdx.x & 63;
    const int q = lane >> 4, nn = lane & 15;
    const int row0 = bid * 64 + wave * 16;
    const int arow = row0 + nn;
    const int arc = arow < N ? arow : N - 1;

    f32x4 acc[8];
#pragma unroll
    for (int ct = 0; ct < 8; ++ct) acc[ct] = (f32x4){0.f, 0.f, 0.f, 0.f};

#pragma unroll
    for (int kk = 0; kk < 4; ++kk) {
        short8 af;
        if (XBF16) {
            af = *(const short8*)((const unsigned short*)Xv + (size_t)arc * EMB + kk * 32 + q * 8);
        } else {
            const float* xp = (const float*)Xv + (size_t)arc * EMB + kk * 32 + q * 8;
            float4 u0 = *(const float4*)xp;
            float4 u1 = *(const float4*)(xp + 4);
            af[0] = (short)f2bf(u0.x); af[1] = (short)f2bf(u0.y);
            af[2] = (short)f2bf(u0.z); af[3] = (short)f2bf(u0.w);
            af[4] = (short)f2bf(u1.x); af[5] = (short)f2bf(u1.y);
            af[6] = (short)f2bf(u1.z); af[7] = (short)f2bf(u1.w);
        }
#pragma unroll
        for (int ct = 0; ct < 8; ++ct) {
            short8 bf = ((const short8*)lds)[(kk * 8 + ct) * 64 + lane];
            acc[ct] = __builtin_amdgcn_mfma_f32_16x16x32_bf16(af, bf, acc[ct], 0, 0, 0);
        }
    }

    __syncthreads();   // W reads + all A-frag (X) reads complete block-wide

    float dv[4];
    if (SCALE) {
#pragma unroll
        for (int r = 0; r < 4; ++r) {
            int gm = row0 + q * 4 + r;
            dv[r] = dis[gm < N ? gm : N - 1];
        }
    }
#pragma unroll
    for (int ct = 0; ct < 8; ++ct) {
#pragma unroll
        for (int r = 0; r < 4; ++r) {
            int ml = wave * 16 + q * 4 + r;
            float val = SCALE ? acc[ct][r] * dv[r] : acc[ct][r];
            lds[ml * 136 + ct * 16 + nn] = f2bf(val);
        }
    }
    __syncthreads();

    // coalesced store: 64 rows x 256B, 16B per thread-item
    const int rbase = bid * 64;
    for (int i = threadIdx.x; i < 1024; i += 256) {
        int row = i >> 4, off = i & 15;
        int grow = rbase + row;
        if (grow < N) {
            uint4 v = *(const uint4*)(lds + row * 136 + off * 8);
            *((uint4*)(Y + (size_t)grow * EMB) + off) = v;
        }
    }
}

// K3: blocks [0,NPART) = reservation scatter; [NPART, NPART+gM) = layer-1 GEMM.
__global__ __launch_bounds__(256) void k_mid(
    const int* __restrict__ src, const int* __restrict__ dstp,
    int* __restrict__ gcnt, int* __restrict__ part, int E, int chunk,
    const void* Xv, const unsigned short* __restrict__ W1s,
    unsigned short* __restrict__ Y, int N)
{
    __shared__ __align__(16) unsigned short smem[16384];   // 32 KB (scatter uses 4 KB)
    int b = blockIdx.x;
    if (b < NPART) scatter_body(b, (int*)smem, src, dstp, gcnt, part, E, chunk);
    else           gemm_body<false, false>(b - NPART, smem, Xv, W1s, nullptr, Y, N);
}

// Layer-2 GEMM (bf16 input, in-place, dis-scaled epilogue).
__global__ __launch_bounds__(256) void k_gemm2(
    const void* Xv, const unsigned short* __restrict__ Wsw,
    const float* __restrict__ dis, unsigned short* __restrict__ Y, int N)
{
    __shared__ __align__(16) unsigned short smem[16384];
    gemm_body<true, true>(blockIdx.x, smem, Xv, Wsw, dis, Y, N);
}

// ---------------- fused gather + norm + bias (+relu), 8-deep MLP ----------------
// 32 threads/node: a wave's 64 lanes cover 2 nodes reading full contiguous 256-B
// rows.  Unroll-8 puts ~16 independent scattered loads in flight per thread.
// FOLD=true  (layer 1): Y unscaled -> a += dis[s]*Y[s]; self += dis[n]*Y[n].
// FOLD=false (layer 2): Y pre-scaled by dis in gemm2 -> plain adds, no dis[s].
// Both: out = dis[n]*a + b.
template <bool FOLD, bool RELU, bool BF16OUT>
__global__ __launch_bounds__(256) void k_gather_finalize(
    const int* __restrict__ R, const int* __restrict__ adj,
    const unsigned short* __restrict__ Y, const float* __restrict__ dis,
    const float* __restrict__ bias, void* __restrict__ Outv, int N)
{
    int t = blockIdx.x * 256 + threadIdx.x;
    int n = t >> 5;
    if (n >= N) return;
    int j = (t & 31) * 4;

    int rs = R[n], re = R[n + 1];
    float dv = dis[n];

    float a0 = 0.f, a1 = 0.f, a2 = 0.f, a3 = 0.f;
    uint2 sv = *(const uint2*)(Y + (size_t)n * EMB + j);
    if (FOLD) acc_fma4(sv, dv, a0, a1, a2, a3);
    else      acc_bf4(sv, a0, a1, a2, a3);

    int e = rs;
    for (; e + 7 < re; e += 8) {
        int s0 = adj[e],     s1 = adj[e + 1], s2 = adj[e + 2], s3 = adj[e + 3];
        int s4 = adj[e + 4], s5 = adj[e + 5], s6 = adj[e + 6], s7 = adj[e + 7];
        uint2 v0 = *(const uint2*)(Y + (size_t)s0 * EMB + j);
        uint2 v1 = *(const uint2*)(Y + (size_t)s1 * EMB + j);
        uint2 v2 = *(const uint2*)(Y + (size_t)s2 * EMB + j);
        uint2 v3 = *(const uint2*)(Y + (size_t)s3 * EMB + j);
        uint2 v4 = *(const uint2*)(Y + (size_t)s4 * EMB + j);
        uint2 v5 = *(const uint2*)(Y + (size_t)s5 * EMB + j);
        uint2 v6 = *(const uint2*)(Y + (size_t)s6 * EMB + j);
        uint2 v7 = *(const uint2*)(Y + (size_t)s7 * EMB + j);
        if (FOLD) {
            float d0 = dis[s0], d1 = dis[s1], d2 = dis[s2], d3 = dis[s3];
            float d4 = dis[s4], d5 = dis[s5], d6 = dis[s6], d7 = dis[s7];
            acc_fma4(v0, d0, a0, a1, a2, a3); acc_fma4(v1, d1, a0, a1, a2, a3);
            acc_fma4(v2, d2, a0, a1, a2, a3); acc_fma4(v3, d3, a0, a1, a2, a3);
            acc_fma4(v4, d4, a0, a1, a2, a3); acc_fma4(v5, d5, a0, a1, a2, a3);
            acc_fma4(v6, d6, a0, a1, a2, a3); acc_fma4(v7, d7, a0, a1, a2, a3);
        } else {
            acc_bf4(v0, a0, a1, a2, a3); acc_bf4(v1, a0, a1, a2, a3);
            acc_bf4(v2, a0, a1, a2, a3); acc_bf4(v3, a0, a1, a2, a3);
            acc_bf4(v4, a0, a1, a2, a3); acc_bf4(v5, a0, a1, a2, a3);
            acc_bf4(v6, a0, a1, a2, a3); acc_bf4(v7, a0, a1, a2, a3);
        }
    }
    for (; e + 3 < re; e += 4) {
        int s0 = adj[e], s1 = adj[e + 1], s2 = adj[e + 2], s3 = adj[e + 3];
        uint2 v0 = *(const uint2*)(Y + (size_t)s0 * EMB + j);
        uint2 v1 = *(const uint2*)(Y + (size_t)s1 * EMB + j);
        uint2 v2 = *(const uint2*)(Y + (size_t)s2 * EMB + j);
        uint2 v3 = *(const uint2*)(Y + (size_t)s3 * EMB + j);
        if (FOLD) {
            float d0 = dis[s0], d1 = dis[s1], d2 = dis[s2], d3 = dis[s3];
            acc_fma4(v0, d0, a0, a1, a2, a3); acc_fma4(v1, d1, a0, a1, a2, a3);
            acc_fma4(v2, d2, a0, a1, a2, a3); acc_fma4(v3, d3, a0, a1, a2, a3);
        } else {
            acc_bf4(v0, a0, a1, a2, a3); acc_bf4(v1, a0, a1, a2, a3);
            acc_bf4(v2, a0, a1, a2, a3); acc_bf4(v3, a0, a1, a2, a3);
        }
    }
    for (; e < re; ++e) {
        int s0 = adj[e];
        uint2 v0 = *(const uint2*)(Y + (size_t)s0 * EMB + j);
        if (FOLD) acc_fma4(v0, dis[s0], a0, a1, a2, a3);
        else      acc_bf4(v0, a0, a1, a2, a3);
    }

    float4 b = *(const float4*)(bias + j);
    float o0 = dv * a0 + b.x;
    float o1 = dv * a1 + b.y;
    float o2 = dv * a2 + b.z;
    float o3 = dv * a3 + b.w;
    if (RELU) {
        o0 = fmaxf(o0, 0.f); o1 = fmaxf(o1, 0.f);
        o2 = fmaxf(o2, 0.f); o3 = fmaxf(o3, 0.f);
    }
    if (BF16OUT) {
        ushort4 o = { f2bf(o0), f2bf(o1), f2bf(o2), f2bf(o3) };
        *(ushort4*)((unsigned short*)Outv + (size_t)n * EMB + j) = o;
    } else {
        float4 o = { o0, o1, o2, o3 };
        *(float4*)((float*)Outv + (size_t)n * EMB + j) = o;
    }
}

extern "C" void kernel_launch(void* const* d_in, const int* in_sizes, int n_in,
                              void* d_out, int out_size, void* d_ws, size_t ws_size,
                              hipStream_t stream) {
    const int* ei = (const int*)d_in[0];
    const int E = in_sizes[0] / 2;
    const float* emb = (const float*)d_in[2];
    const int N = in_sizes[2] / EMB;
    const float* W1 = (const float*)d_in[3];
    const float* b1 = (const float*)d_in[4];
    const float* W2 = (const float*)d_in[5];
    const float* b2 = (const float*)d_in[6];
    float* out = (float*)d_out;

    const int* src = ei;
    const int* dstp = ei + E;

    // ws: dis | R | base | tot | gcnt | adj | W1s | W2s | Hb (part overlays Hb;
    // dead before gather1 writes Hb).  Y1b lives in d_out (dead before gather2
    // writes d_out f32).
    char* w = (char*)d_ws;
    auto take = [&](size_t bytes) { char* p = w; w += (bytes + 511) & ~(size_t)511; return p; };
    float* dis  = (float*)take((size_t)N * 4);
    int*   R    = (int*)  take((size_t)(N + 1) * 4);
    int*   base = (int*)  take((size_t)(NBUC + 1) * 4);
    int*   tot  = (int*)  take((size_t)NBUC * 4);
    int*   gcnt = (int*)  take((size_t)NBUC * 4);
    int*   adj  = (int*)  take((size_t)E * 4);
    unsigned short* W1s = (unsigned short*)take((size_t)EMB * EMB * 2);
    unsigned short* W2s = (unsigned short*)take((size_t)EMB * EMB * 2);
    unsigned short* Hb  = (unsigned short*)take((size_t)N * EMB * 2);
    int*   part = (int*)Hb;                                  // overlay (dead before Hb)
    unsigned short* Y1b = (unsigned short*)d_out;            // overlay in d_out

    const int NB = (N + 127) / 128;
    const int chunk = (E + NPART - 1) / NPART;
    const int gM = (N + 63) / 64;            // MFMA gemm blocks
    const int gG = (N * 32 + 255) / 256;     // gather blocks

    // --- stage 0: zero bucket totals (graph-capture-legal async memset) ---
    hipMemsetAsync(tot, 0, (size_t)NBUC * 4, stream);

    // --- K1: edge histogram -> tot, in parallel with weight pre-swizzle ---
    k_start<<<NPART + PREPB, 256, 0, stream>>>(dstp, tot, E, chunk, W1, W2, W1s, W2s);

    // --- K2: scan totals -> base, init cursors gcnt ---
    p_scan<<<1, NBUC, 0, stream>>>(tot, base, gcnt, E);

    // --- K3: reservation scatter in parallel with layer-1 GEMM (unscaled Y1b) ---
    k_mid<<<NPART + gM, 256, 0, stream>>>(src, dstp, gcnt, part, E, chunk,
                                          emb, W1s, Y1b, N);

    // --- K4: bucket -> CSR (R, adj, dis) ---
    p3_csr<<<NB, 256, 0, stream>>>(part, base, R, adj, dis, N, E);

    // --- layer 1 gather: Hb = bf16(relu(dis*(sum dis[s]*Y1b[s] + dis*Y1b[n]) + b1)) ---
    k_gather_finalize<true, true, true><<<gG, 256, 0, stream>>>(R, adj, Y1b, dis, b1, Hb, N);

    // --- layer 2: Hb = bf16((Hb@W2)*dis) in-place; out = dis*(sum+self) + b2 (f32) ---
    k_gemm2<<<gM, 256, 0, stream>>>(Hb, W2s, dis, Hb, N);
    k_gather_finalize<false, false, false><<<gG, 256, 0, stream>>>(R, adj, Hb, dis, b2, out, N);
}

// Round 7
// 325.632 us; speedup vs baseline: 2.4828x; 1.0062x over previous
//
#include <hip/hip_runtime.h>

#define EMB 128
#define NBUC 1024          // coarse buckets: dst >> 7 (128 nodes per bucket)
#define NPART 256          // partition blocks for hist/scatter
#define PREPB 128          // prep_w blocks appended to k_start

typedef __attribute__((ext_vector_type(8))) short short8;   // 8 bf16 (4 VGPRs)
typedef __attribute__((ext_vector_type(4))) float f32x4;    // MFMA acc

// ---------------- bf16 helpers ----------------
__device__ __forceinline__ unsigned short f2bf(float f) {
    union { float f; unsigned int i; } v; v.f = f;
    unsigned int x = v.i;
    x += 0x7fffu + ((x >> 16) & 1u);   // round-to-nearest-even
    return (unsigned short)(x >> 16);
}
// a += d * unpack_bf16x4(v)
__device__ __forceinline__ void acc_fma4(uint2 v, float d,
                                         float& a0, float& a1, float& a2, float& a3) {
    union { unsigned int i; float f; } t;
    t.i = v.x << 16;          a0 = fmaf(d, t.f, a0);
    t.i = v.x & 0xffff0000u;  a1 = fmaf(d, t.f, a1);
    t.i = v.y << 16;          a2 = fmaf(d, t.f, a2);
    t.i = v.y & 0xffff0000u;  a3 = fmaf(d, t.f, a3);
}
// a += unpack_bf16x4(v)
__device__ __forceinline__ void acc_bf4(uint2 v,
                                        float& a0, float& a1, float& a2, float& a3) {
    union { unsigned int i; float f; } t;
    t.i = v.x << 16;          a0 += t.f;
    t.i = v.x & 0xffff0000u;  a1 += t.f;
    t.i = v.y << 16;          a2 += t.f;
    t.i = v.y & 0xffff0000u;  a3 += t.f;
}

// ============ CSR build: reservation counting sort (no BH matrix) ============

// hist chunk into LDS, then one global atomicAdd per nonzero bucket.
__device__ __forceinline__ void p1_body(int bid, int* h, const int* __restrict__ dst,
                                        int* __restrict__ tot, int E, int chunk) {
    for (int i = threadIdx.x; i < NBUC; i += 256) h[i] = 0;
    __syncthreads();
    int s = bid * chunk;
    int e = min(E, s + chunk);
    for (int i = s + threadIdx.x; i < e; i += 256)
        atomicAdd(&h[dst[i] >> 7], 1);
    __syncthreads();
    for (int i = threadIdx.x; i < NBUC; i += 256) {
        int v = h[i];
        if (v) atomicAdd(&tot[i], v);
    }
}

// W pre-swizzle: f32 [128][128] -> bf16 fragment order.
// Wb[kk][ct][q][nn][j] = W[kk*32+q*8+j][ct*16+nn]; lane (q*16+nn) reads its B-frag
// for (kk,ct) as one contiguous 16B short8 at index (kk*8+ct)*64 + lane.
__device__ __forceinline__ void prepw_body(int bid, const float* __restrict__ W1,
                                           const float* __restrict__ W2,
                                           unsigned short* __restrict__ W1s,
                                           unsigned short* __restrict__ W2s) {
    int gid = bid * 256 + threadIdx.x;            // 128 blocks x 256 = 32768
    const float* W = (gid < 16384) ? W1 : W2;
    unsigned short* Ws = (gid < 16384) ? W1s : W2s;
    int idx = gid & 16383;
    int k = idx >> 7, n = idx & 127;
    int kk = k >> 5, q = (k >> 3) & 3, j = k & 7;
    int ct = n >> 4, nn = n & 15;
    int didx = ((((kk * 8 + ct) * 4 + q) * 16 + nn) << 3) + j;
    Ws[didx] = f2bf(W[idx]);
}

// K1: blocks [0,NPART) = hist; [NPART, NPART+PREPB) = weight pre-swizzle.
__global__ __launch_bounds__(256) void k_start(const int* __restrict__ dst,
                                               int* __restrict__ tot, int E, int chunk,
                                               const float* __restrict__ W1,
                                               const float* __restrict__ W2,
                                               unsigned short* __restrict__ W1s,
                                               unsigned short* __restrict__ W2s) {
    __shared__ int h[NBUC];
    int b = blockIdx.x;
    if (b < NPART) p1_body(b, h, dst, tot, E, chunk);
    else           prepw_body(b - NPART, W1, W2, W1s, W2s);
}

// Exclusive scan of bucket totals -> base[]; also init the global cursors gcnt[].
__global__ __launch_bounds__(1024) void p_scan(const int* __restrict__ tot,
                                               int* __restrict__ base,
                                               int* __restrict__ gcnt, int E) {
    __shared__ int a[NBUC];
    int t = threadIdx.x;
    int v0 = tot[t];
    a[t] = v0;
    __syncthreads();
    for (int off = 1; off < NBUC; off <<= 1) {
        int v = (t >= off) ? a[t - off] : 0;
        __syncthreads();
        a[t] += v;
        __syncthreads();
    }
    int excl = a[t] - v0;
    base[t] = excl;
    gcnt[t] = excl;
    if (t == NBUC - 1) base[NBUC] = E;
}

// Reservation scatter: pass1 count chunk's buckets in LDS; reserve ranges via one
// global atomicAdd per (block,bucket); pass2 re-read chunk (L1/L2-hot) and place.
// Intra-bucket order is arbitrary (p3 re-sorts by node; sums are order-indep).
__device__ __forceinline__ void scatter_body(int bid, int* cnt,
                                             const int* __restrict__ src,
                                             const int* __restrict__ dst,
                                             int* __restrict__ gcnt,
                                             int* __restrict__ part,
                                             int E, int chunk) {
    for (int i = threadIdx.x; i < NBUC; i += 256) cnt[i] = 0;
    __syncthreads();
    int s = bid * chunk;
    int e = min(E, s + chunk);
    for (int i = s + threadIdx.x; i < e; i += 256)
        atomicAdd(&cnt[dst[i] >> 7], 1);
    __syncthreads();
    for (int i = threadIdx.x; i < NBUC; i += 256) {
        int c = cnt[i];
        cnt[i] = c ? atomicAdd(&gcnt[i], c) : 0;   // LDS cursor := global base
    }
    __syncthreads();
    for (int i = s + threadIdx.x; i < e; i += 256) {
        int d = dst[i];
        int pos = atomicAdd(&cnt[d >> 7], 1);
        part[pos] = src[i] | ((d & 127) << 17);    // src < 2^17, local node in [0,128)
    }
}

__global__ __launch_bounds__(256) void p3_csr(const int* __restrict__ part,
                                              const int* __restrict__ base,
                                              int* __restrict__ R, int* __restrict__ adj,
                                              float* __restrict__ dis, int N, int E) {
    __shared__ int hist[128];
    __shared__ int sc[128];
    __shared__ int cnt[128];
    int b = blockIdx.x;
    int n0 = b * 128;
    int nn = min(128, N - n0);
    int s = base[b], e = base[b + 1];
    int t = threadIdx.x;

    if (t < 128) hist[t] = 0;
    __syncthreads();
    for (int i = s + t; i < e; i += 256)
        atomicAdd(&hist[part[i] >> 17], 1);
    __syncthreads();

    if (t < 128) sc[t] = hist[t];
    __syncthreads();
    for (int off = 1; off < 128; off <<= 1) {
        int v = 0;
        if (t < 128 && t >= off) v = sc[t - off];
        __syncthreads();
        if (t < 128) sc[t] += v;
        __syncthreads();
    }
    if (t < 128) {
        int excl = sc[t] - hist[t];
        cnt[t] = excl;
        if (t < nn) {
            R[n0 + t] = s + excl;
            dis[n0 + t] = rsqrtf((float)hist[t] + 1.0f);   // +1 self-loop
        }
    }
    if (b == 0 && t == 0) R[N] = E;
    __syncthreads();

    for (int i = s + t; i < e; i += 256) {
        int p = part[i];
        int pos = atomicAdd(&cnt[p >> 17], 1);
        adj[s + pos] = p & 0x1FFFF;
    }
}

// ---------------- MFMA GEMM body: Y[n] = bf16((X[n] @ W) [* dis[n]]) ----------------
// 64 nodes/block, 16/wave; K=128 as 4 steps of mfma_f32_16x16x32_bf16.
// Fragment maps (doc-verified): A: m=lane&15, k=q*8+j; B: n=lane&15, k=q*8+j;
// D: n=lane&15, m=q*4+reg.  SCALE=false for layer 1 (dis not ready; norm folded
// into gather1); SCALE=true for layer 2 (dis ready -> gather2 needs no dis[s]).
// In-place safe (X==Y): a block touches only its own 64 rows; all A-frag reads
// happen before the store-side __syncthreads().
template <bool XBF16, bool SCALE>
__device__ __forceinline__ void gemm_body(int bid, unsigned short* lds,
    const void* Xv, const unsigned short* __restrict__ Wsw,
    const float* __restrict__ dis, unsigned short* __restrict__ Y, int N)
{
    // stage swizzled W (coalesced 16B copies)
    {
        const uint4* srcp = (const uint4*)Wsw;
        uint4* dstp = (uint4*)lds;
        for (int i = threadIdx.x; i < 2048; i += 256) dstp[i] = srcp[i];
    }
    __syncthreads();

    const int wave = threadIdx.x >> 6;
    const int lane = threadIdx.x & 63;
    const int q = lane >> 4, nn = lane & 15;
    const int row0 = bid * 64 + wave * 16;
    const int arow = row0 + nn;
    const int arc = arow < N ? arow : N - 1;

    f32x4 acc[8];
#pragma unroll
    for (int ct = 0; ct < 8; ++ct) acc[ct] = (f32x4){0.f, 0.f, 0.f, 0.f};

#pragma unroll
    for (int kk = 0; kk < 4; ++kk) {
        short8 af;
        if (XBF16) {
            af = *(const short8*)((const unsigned short*)Xv + (size_t)arc * EMB + kk * 32 + q * 8);
        } else {
            const float* xp = (const float*)Xv + (size_t)arc * EMB + kk * 32 + q * 8;
            float4 u0 = *(const float4*)xp;
            float4 u1 = *(const float4*)(xp + 4);
            af[0] = (short)f2bf(u0.x); af[1] = (short)f2bf(u0.y);
            af[2] = (short)f2bf(u0.z); af[3] = (short)f2bf(u0.w);
            af[4] = (short)f2bf(u1.x); af[5] = (short)f2bf(u1.y);
            af[6] = (short)f2bf(u1.z); af[7] = (short)f2bf(u1.w);
        }
#pragma unroll
        for (int ct = 0; ct < 8; ++ct) {
            short8 bf = ((const short8*)lds)[(kk * 8 + ct) * 64 + lane];
            acc[ct] = __builtin_amdgcn_mfma_f32_16x16x32_bf16(af, bf, acc[ct], 0, 0, 0);
        }
    }

    __syncthreads();   // W reads + all A-frag (X) reads complete block-wide

    float dv[4];
    if (SCALE) {
#pragma unroll
        for (int r = 0; r < 4; ++r) {
            int gm = row0 + q * 4 + r;
            dv[r] = dis[gm < N ? gm : N - 1];
        }
    }
#pragma unroll
    for (int ct = 0; ct < 8; ++ct) {
#pragma unroll
        for (int r = 0; r < 4; ++r) {
            int ml = wave * 16 + q * 4 + r;
            float val = SCALE ? acc[ct][r] * dv[r] : acc[ct][r];
            lds[ml * 136 + ct * 16 + nn] = f2bf(val);
        }
    }
    __syncthreads();

    // coalesced store: 64 rows x 256B, 16B per thread-item
    const int rbase = bid * 64;
    for (int i = threadIdx.x; i < 1024; i += 256) {
        int row = i >> 4, off = i & 15;
        int grow = rbase + row;
        if (grow < N) {
            uint4 v = *(const uint4*)(lds + row * 136 + off * 8);
            *((uint4*)(Y + (size_t)grow * EMB) + off) = v;
        }
    }
}

// K3: blocks [0,NPART) = reservation scatter; [NPART, NPART+gM) = layer-1 GEMM.
__global__ __launch_bounds__(256) void k_mid(
    const int* __restrict__ src, const int* __restrict__ dstp,
    int* __restrict__ gcnt, int* __restrict__ part, int E, int chunk,
    const void* Xv, const unsigned short* __restrict__ W1s,
    unsigned short* __restrict__ Y, int N)
{
    __shared__ __align__(16) unsigned short smem[16384];   // 32 KB (scatter uses 4 KB)
    int b = blockIdx.x;
    if (b < NPART) scatter_body(b, (int*)smem, src, dstp, gcnt, part, E, chunk);
    else           gemm_body<false, false>(b - NPART, smem, Xv, W1s, nullptr, Y, N);
}

// Layer-2 GEMM (bf16 input, in-place, dis-scaled epilogue).
__global__ __launch_bounds__(256) void k_gemm2(
    const void* Xv, const unsigned short* __restrict__ Wsw,
    const float* __restrict__ dis, unsigned short* __restrict__ Y, int N)
{
    __shared__ __align__(16) unsigned short smem[16384];
    gemm_body<true, true>(blockIdx.x, smem, Xv, Wsw, dis, Y, N);
}

// -------- gather + norm + bias (+relu), DIM-SPLIT into two sequential passes --------
// Blocks [0,half) process dims [0,64); blocks [half,2*half) process dims [64,128).
// Each pass's read working set is 12.8 MB (vs 25.6), so each XCD's 4MB L2 covers
// 2x the fraction -> higher hit rate.  Per node-pass read = 16 lanes x 8B = 128B
// contiguous & 128B-aligned: full-line granule, no over-fetch (round-1's flaw).
// In-order block dispatch gives the temporal separation; no XCD pinning needed.
// 16 threads/node; unroll-4 (VGPR ~20 -> ~70% occupancy; unroll-8 regressed).
// FOLD=true  (layer 1): Y unscaled -> a += dis[s]*Y[s]; self += dis[n]*Y[n].
// FOLD=false (layer 2): Y pre-scaled by dis in gemm2 -> plain adds.
// Both: out = dis[n]*a + b.
template <bool FOLD, bool RELU, bool BF16OUT>
__global__ __launch_bounds__(256) void k_gather_split(
    const int* __restrict__ R, const int* __restrict__ adj,
    const unsigned short* __restrict__ Y, const float* __restrict__ dis,
    const float* __restrict__ bias, void* __restrict__ Outv, int N, int half)
{
    int bid = blockIdx.x;
    int pass = (bid >= half) ? 1 : 0;
    int t = (bid - pass * half) * 256 + threadIdx.x;
    int n = t >> 4;                          // 16 threads/node
    if (n >= N) return;
    int j = pass * 64 + (t & 15) * 4;        // 4 dims per thread

    int rs = R[n], re = R[n + 1];
    float dv = dis[n];

    float a0 = 0.f, a1 = 0.f, a2 = 0.f, a3 = 0.f;
    uint2 sv = *(const uint2*)(Y + (size_t)n * EMB + j);
    if (FOLD) acc_fma4(sv, dv, a0, a1, a2, a3);
    else      acc_bf4(sv, a0, a1, a2, a3);

    int e = rs;
    for (; e + 3 < re; e += 4) {
        int s0 = adj[e], s1 = adj[e + 1], s2 = adj[e + 2], s3 = adj[e + 3];
        uint2 v0 = *(const uint2*)(Y + (size_t)s0 * EMB + j);
        uint2 v1 = *(const uint2*)(Y + (size_t)s1 * EMB + j);
        uint2 v2 = *(const uint2*)(Y + (size_t)s2 * EMB + j);
        uint2 v3 = *(const uint2*)(Y + (size_t)s3 * EMB + j);
        if (FOLD) {
            float d0 = dis[s0], d1 = dis[s1], d2 = dis[s2], d3 = dis[s3];
            acc_fma4(v0, d0, a0, a1, a2, a3); acc_fma4(v1, d1, a0, a1, a2, a3);
            acc_fma4(v2, d2, a0, a1, a2, a3); acc_fma4(v3, d3, a0, a1, a2, a3);
        } else {
            acc_bf4(v0, a0, a1, a2, a3); acc_bf4(v1, a0, a1, a2, a3);
            acc_bf4(v2, a0, a1, a2, a3); acc_bf4(v3, a0, a1, a2, a3);
        }
    }
    for (; e < re; ++e) {
        int s0 = adj[e];
        uint2 v0 = *(const uint2*)(Y + (size_t)s0 * EMB + j);
        if (FOLD) acc_fma4(v0, dis[s0], a0, a1, a2, a3);
        else      acc_bf4(v0, a0, a1, a2, a3);
    }

    float4 b = *(const float4*)(bias + j);
    float o0 = dv * a0 + b.x;
    float o1 = dv * a1 + b.y;
    float o2 = dv * a2 + b.z;
    float o3 = dv * a3 + b.w;
    if (RELU) {
        o0 = fmaxf(o0, 0.f); o1 = fmaxf(o1, 0.f);
        o2 = fmaxf(o2, 0.f); o3 = fmaxf(o3, 0.f);
    }
    if (BF16OUT) {
        ushort4 o = { f2bf(o0), f2bf(o1), f2bf(o2), f2bf(o3) };
        *(ushort4*)((unsigned short*)Outv + (size_t)n * EMB + j) = o;
    } else {
        float4 o = { o0, o1, o2, o3 };
        *(float4*)((float*)Outv + (size_t)n * EMB + j) = o;
    }
}

extern "C" void kernel_launch(void* const* d_in, const int* in_sizes, int n_in,
                              void* d_out, int out_size, void* d_ws, size_t ws_size,
                              hipStream_t stream) {
    const int* ei = (const int*)d_in[0];
    const int E = in_sizes[0] / 2;
    const float* emb = (const float*)d_in[2];
    const int N = in_sizes[2] / EMB;
    const float* W1 = (const float*)d_in[3];
    const float* b1 = (const float*)d_in[4];
    const float* W2 = (const float*)d_in[5];
    const float* b2 = (const float*)d_in[6];
    float* out = (float*)d_out;

    const int* src = ei;
    const int* dstp = ei + E;

    // ws: dis | R | base | tot | gcnt | adj | W1s | W2s | Hb (part overlays Hb;
    // dead before gather1 writes Hb).  Y1b lives in d_out (dead before gather2
    // writes d_out f32).
    char* w = (char*)d_ws;
    auto take = [&](size_t bytes) { char* p = w; w += (bytes + 511) & ~(size_t)511; return p; };
    float* dis  = (float*)take((size_t)N * 4);
    int*   R    = (int*)  take((size_t)(N + 1) * 4);
    int*   base = (int*)  take((size_t)(NBUC + 1) * 4);
    int*   tot  = (int*)  take((size_t)NBUC * 4);
    int*   gcnt = (int*)  take((size_t)NBUC * 4);
    int*   adj  = (int*)  take((size_t)E * 4);
    unsigned short* W1s = (unsigned short*)take((size_t)EMB * EMB * 2);
    unsigned short* W2s = (unsigned short*)take((size_t)EMB * EMB * 2);
    unsigned short* Hb  = (unsigned short*)take((size_t)N * EMB * 2);
    int*   part = (int*)Hb;                                  // overlay (dead before Hb)
    unsigned short* Y1b = (unsigned short*)d_out;            // overlay in d_out

    const int NB = (N + 127) / 128;
    const int chunk = (E + NPART - 1) / NPART;
    const int gM = (N + 63) / 64;            // MFMA gemm blocks
    const int half = (N * 16 + 255) / 256;   // gather blocks per dim-pass
    const int gG = 2 * half;

    // --- stage 0: zero bucket totals (graph-capture-legal async memset) ---
    hipMemsetAsync(tot, 0, (size_t)NBUC * 4, stream);

    // --- K1: edge histogram -> tot, in parallel with weight pre-swizzle ---
    k_start<<<NPART + PREPB, 256, 0, stream>>>(dstp, tot, E, chunk, W1, W2, W1s, W2s);

    // --- K2: scan totals -> base, init cursors gcnt ---
    p_scan<<<1, NBUC, 0, stream>>>(tot, base, gcnt, E);

    // --- K3: reservation scatter in parallel with layer-1 GEMM (unscaled Y1b) ---
    k_mid<<<NPART + gM, 256, 0, stream>>>(src, dstp, gcnt, part, E, chunk,
                                          emb, W1s, Y1b, N);

    // --- K4: bucket -> CSR (R, adj, dis) ---
    p3_csr<<<NB, 256, 0, stream>>>(part, base, R, adj, dis, N, E);

    // --- layer 1 gather (dim-split): Hb = bf16(relu(dis*(sum dis[s]*Y1b[s] + dis*Y1b[n]) + b1)) ---
    k_gather_split<true, true, true><<<gG, 256, 0, stream>>>(R, adj, Y1b, dis, b1, Hb, N, half);

    // --- layer 2: Hb = bf16((Hb@W2)*dis) in-place; out = dis*(sum+self) + b2 (f32) ---
    k_gemm2<<<gM, 256, 0, stream>>>(Hb, W2s, dis, Hb, N);
    k_gather_split<false, false, false><<<gG, 256, 0, stream>>>(R, adj, Hb, dis, b2, out, N, half);
}

// Round 8
// 320.295 us; speedup vs baseline: 2.5242x; 1.0167x over previous
//
#include <hip/hip_runtime.h>

#define EMB 128
#define NBUC 1024          // coarse buckets: dst >> 7 (128 nodes per bucket)
#define NPART 256          // partition blocks for hist/scatter
#define PREPB 128          // prep_w blocks appended to k_start

typedef __attribute__((ext_vector_type(8))) short short8;   // 8 bf16 (4 VGPRs)
typedef __attribute__((ext_vector_type(4))) float f32x4;    // MFMA acc

// ---------------- bf16 helpers ----------------
__device__ __forceinline__ unsigned short f2bf(float f) {
    union { float f; unsigned int i; } v; v.f = f;
    unsigned int x = v.i;
    x += 0x7fffu + ((x >> 16) & 1u);   // round-to-nearest-even
    return (unsigned short)(x >> 16);
}
// a[0..7] += d * unpack_bf16x8(v)
__device__ __forceinline__ void acc_fma8(uint4 v, float d, float* a) {
    union { unsigned int i; float f; } t;
    t.i = v.x << 16;          a[0] = fmaf(d, t.f, a[0]);
    t.i = v.x & 0xffff0000u;  a[1] = fmaf(d, t.f, a[1]);
    t.i = v.y << 16;          a[2] = fmaf(d, t.f, a[2]);
    t.i = v.y & 0xffff0000u;  a[3] = fmaf(d, t.f, a[3]);
    t.i = v.z << 16;          a[4] = fmaf(d, t.f, a[4]);
    t.i = v.z & 0xffff0000u;  a[5] = fmaf(d, t.f, a[5]);
    t.i = v.w << 16;          a[6] = fmaf(d, t.f, a[6]);
    t.i = v.w & 0xffff0000u;  a[7] = fmaf(d, t.f, a[7]);
}
// a[0..7] += unpack_bf16x8(v)
__device__ __forceinline__ void acc_add8(uint4 v, float* a) {
    union { unsigned int i; float f; } t;
    t.i = v.x << 16;          a[0] += t.f;
    t.i = v.x & 0xffff0000u;  a[1] += t.f;
    t.i = v.y << 16;          a[2] += t.f;
    t.i = v.y & 0xffff0000u;  a[3] += t.f;
    t.i = v.z << 16;          a[4] += t.f;
    t.i = v.z & 0xffff0000u;  a[5] += t.f;
    t.i = v.w << 16;          a[6] += t.f;
    t.i = v.w & 0xffff0000u;  a[7] += t.f;
}

// ============ CSR build: reservation counting sort ============

__device__ __forceinline__ void p1_body(int bid, int* h, const int* __restrict__ dst,
                                        int* __restrict__ tot, int E, int chunk) {
    for (int i = threadIdx.x; i < NBUC; i += 256) h[i] = 0;
    __syncthreads();
    int s = bid * chunk;
    int e = min(E, s + chunk);
    for (int i = s + threadIdx.x; i < e; i += 256)
        atomicAdd(&h[dst[i] >> 7], 1);
    __syncthreads();
    for (int i = threadIdx.x; i < NBUC; i += 256) {
        int v = h[i];
        if (v) atomicAdd(&tot[i], v);
    }
}

// W pre-swizzle: f32 [128][128] -> bf16 fragment order.
// Wb[kk][ct][q][nn][j] = W[kk*32+q*8+j][ct*16+nn]; lane (q*16+nn) reads its B-frag
// for (kk,ct) as one contiguous 16B short8 at index (kk*8+ct)*64 + lane.
__device__ __forceinline__ void prepw_body(int bid, const float* __restrict__ W1,
                                           const float* __restrict__ W2,
                                           unsigned short* __restrict__ W1s,
                                           unsigned short* __restrict__ W2s) {
    int gid = bid * 256 + threadIdx.x;            // 128 blocks x 256 = 32768
    const float* W = (gid < 16384) ? W1 : W2;
    unsigned short* Ws = (gid < 16384) ? W1s : W2s;
    int idx = gid & 16383;
    int k = idx >> 7, n = idx & 127;
    int kk = k >> 5, q = (k >> 3) & 3, j = k & 7;
    int ct = n >> 4, nn = n & 15;
    int didx = ((((kk * 8 + ct) * 4 + q) * 16 + nn) << 3) + j;
    Ws[didx] = f2bf(W[idx]);
}

// K1: blocks [0,NPART) = hist; [NPART, NPART+PREPB) = weight pre-swizzle.
__global__ __launch_bounds__(256) void k_start(const int* __restrict__ dst,
                                               int* __restrict__ tot, int E, int chunk,
                                               const float* __restrict__ W1,
                                               const float* __restrict__ W2,
                                               unsigned short* __restrict__ W1s,
                                               unsigned short* __restrict__ W2s) {
    __shared__ int h[NBUC];
    int b = blockIdx.x;
    if (b < NPART) p1_body(b, h, dst, tot, E, chunk);
    else           prepw_body(b - NPART, W1, W2, W1s, W2s);
}

// Exclusive scan of bucket totals -> base[]; init global cursors gcnt[].
__global__ __launch_bounds__(1024) void p_scan(const int* __restrict__ tot,
                                               int* __restrict__ base,
                                               int* __restrict__ gcnt, int E) {
    __shared__ int a[NBUC];
    int t = threadIdx.x;
    int v0 = tot[t];
    a[t] = v0;
    __syncthreads();
    for (int off = 1; off < NBUC; off <<= 1) {
        int v = (t >= off) ? a[t - off] : 0;
        __syncthreads();
        a[t] += v;
        __syncthreads();
    }
    int excl = a[t] - v0;
    base[t] = excl;
    gcnt[t] = excl;
    if (t == NBUC - 1) base[NBUC] = E;
}

// Reservation scatter (intra-bucket order arbitrary; p3 re-sorts by node).
__device__ __forceinline__ void scatter_body(int bid, int* cnt,
                                             const int* __restrict__ src,
                                             const int* __restrict__ dst,
                                             int* __restrict__ gcnt,
                                             int* __restrict__ part,
                                             int E, int chunk) {
    for (int i = threadIdx.x; i < NBUC; i += 256) cnt[i] = 0;
    __syncthreads();
    int s = bid * chunk;
    int e = min(E, s + chunk);
    for (int i = s + threadIdx.x; i < e; i += 256)
        atomicAdd(&cnt[dst[i] >> 7], 1);
    __syncthreads();
    for (int i = threadIdx.x; i < NBUC; i += 256) {
        int c = cnt[i];
        cnt[i] = c ? atomicAdd(&gcnt[i], c) : 0;   // LDS cursor := global base
    }
    __syncthreads();
    for (int i = s + threadIdx.x; i < e; i += 256) {
        int d = dst[i];
        int pos = atomicAdd(&cnt[d >> 7], 1);
        part[pos] = src[i] | ((d & 127) << 17);    // src < 2^17, local node in [0,128)
    }
}

__global__ __launch_bounds__(256) void p3_csr(const int* __restrict__ part,
                                              const int* __restrict__ base,
                                              int* __restrict__ R, int* __restrict__ adj,
                                              float* __restrict__ dis, int N, int E) {
    __shared__ int hist[128];
    __shared__ int sc[128];
    __shared__ int cnt[128];
    int b = blockIdx.x;
    int n0 = b * 128;
    int nn = min(128, N - n0);
    int s = base[b], e = base[b + 1];
    int t = threadIdx.x;

    if (t < 128) hist[t] = 0;
    __syncthreads();
    for (int i = s + t; i < e; i += 256)
        atomicAdd(&hist[part[i] >> 17], 1);
    __syncthreads();

    if (t < 128) sc[t] = hist[t];
    __syncthreads();
    for (int off = 1; off < 128; off <<= 1) {
        int v = 0;
        if (t < 128 && t >= off) v = sc[t - off];
        __syncthreads();
        if (t < 128) sc[t] += v;
        __syncthreads();
    }
    if (t < 128) {
        int excl = sc[t] - hist[t];
        cnt[t] = excl;
        if (t < nn) {
            R[n0 + t] = s + excl;
            dis[n0 + t] = rsqrtf((float)hist[t] + 1.0f);   // +1 self-loop
        }
    }
    if (b == 0 && t == 0) R[N] = E;
    __syncthreads();

    for (int i = s + t; i < e; i += 256) {
        int p = part[i];
        int pos = atomicAdd(&cnt[p >> 17], 1);
        adj[s + pos] = p & 0x1FFFF;
    }
}

// ---------------- MFMA GEMM body: Y[n] = bf16(X[n] @ W), UNSCALED ----------------
// 64 nodes/block, 16/wave; K=128 as 4 steps of mfma_f32_16x16x32_bf16.
// Fragment maps (doc-verified): A: m=lane&15, k=q*8+j; B: n=lane&15, k=q*8+j;
// D: n=lane&15, m=q*4+reg.  Used for layer 1 only (dis folded into gather1).
__device__ __forceinline__ void gemm_body(int bid, unsigned short* lds,
    const float* __restrict__ Xv, const unsigned short* __restrict__ Wsw,
    unsigned short* __restrict__ Y, int N)
{
    {
        const uint4* srcp = (const uint4*)Wsw;
        uint4* dstp = (uint4*)lds;
        for (int i = threadIdx.x; i < 2048; i += 256) dstp[i] = srcp[i];
    }
    __syncthreads();

    const int wave = threadIdx.x >> 6;
    const int lane = threadIdx.x & 63;
    const int q = lane >> 4, nn = lane & 15;
    const int row0 = bid * 64 + wave * 16;
    const int arow = row0 + nn;
    const int arc = arow < N ? arow : N - 1;

    f32x4 acc[8];
#pragma unroll
    for (int ct = 0; ct < 8; ++ct) acc[ct] = (f32x4){0.f, 0.f, 0.f, 0.f};

#pragma unroll
    for (int kk = 0; kk < 4; ++kk) {
        const float* xp = Xv + (size_t)arc * EMB + kk * 32 + q * 8;
        float4 u0 = *(const float4*)xp;
        float4 u1 = *(const float4*)(xp + 4);
        short8 af;
        af[0] = (short)f2bf(u0.x); af[1] = (short)f2bf(u0.y);
        af[2] = (short)f2bf(u0.z); af[3] = (short)f2bf(u0.w);
        af[4] = (short)f2bf(u1.x); af[5] = (short)f2bf(u1.y);
        af[6] = (short)f2bf(u1.z); af[7] = (short)f2bf(u1.w);
#pragma unroll
        for (int ct = 0; ct < 8; ++ct) {
            short8 bf = ((const short8*)lds)[(kk * 8 + ct) * 64 + lane];
            acc[ct] = __builtin_amdgcn_mfma_f32_16x16x32_bf16(af, bf, acc[ct], 0, 0, 0);
        }
    }

    __syncthreads();

#pragma unroll
    for (int ct = 0; ct < 8; ++ct) {
#pragma unroll
        for (int r = 0; r < 4; ++r) {
            int ml = wave * 16 + q * 4 + r;
            lds[ml * 136 + ct * 16 + nn] = f2bf(acc[ct][r]);
        }
    }
    __syncthreads();

    const int rbase = bid * 64;
    for (int i = threadIdx.x; i < 1024; i += 256) {
        int row = i >> 4, off = i & 15;
        int grow = rbase + row;
        if (grow < N) {
            uint4 v = *(const uint4*)(lds + row * 136 + off * 8);
            *((uint4*)(Y + (size_t)grow * EMB) + off) = v;
        }
    }
}

// K3: blocks [0,NPART) = reservation scatter; [NPART, NPART+gM) = layer-1 GEMM.
__global__ __launch_bounds__(256) void k_mid(
    const int* __restrict__ src, const int* __restrict__ dstp,
    int* __restrict__ gcnt, int* __restrict__ part, int E, int chunk,
    const float* __restrict__ Xv, const unsigned short* __restrict__ W1s,
    unsigned short* __restrict__ Y, int N)
{
    __shared__ __align__(16) unsigned short smem[16384];   // 32 KB (scatter uses 4 KB)
    int b = blockIdx.x;
    if (b < NPART) scatter_body(b, (int*)smem, src, dstp, gcnt, part, E, chunk);
    else           gemm_body(b - NPART, smem, Xv, W1s, Y, N);
}

// ======== FUSED layer-1 gather + relu + layer-2 GEMM (one block = 16 nodes) ========
// Gather phase: 16 threads/node, uint4 (8 dims/thread, 16B/lane coalescing sweet
// spot).  H[n] = relu(dis[n]*(sum_s dis[s]*Y1[s] + dis[n]*Y1[n]) + b1), staged
// bf16 in LDS [16][136].  MFMA phase: the block's 16 H-rows are one M-tile;
// wave w computes output cols [w*32, w*32+32) via 8x mfma_16x16x32 with B-frags
// preloaded from swizzled W2s (32KB, L2-hot).  Epilogue scales rows by dis[n]
// (so the layer-2 gather does plain adds) and stores coalesced bf16.
// No early returns: invalid nodes contribute zero rows and hit all barriers.
__global__ __launch_bounds__(256) void k_gather_gemm(
    const int* __restrict__ R, const int* __restrict__ adj,
    const unsigned short* __restrict__ Y1, const float* __restrict__ dis,
    const float* __restrict__ b1, const unsigned short* __restrict__ W2s,
    unsigned short* __restrict__ Y2, int N)
{
    __shared__ __align__(16) unsigned short Hs[16][136];

    const int wave = threadIdx.x >> 6;
    const int lane = threadIdx.x & 63;
    const int q = lane >> 4, nn = lane & 15;

    // B-frags for this wave's two 16-col tiles (ct = 2*wave, 2*wave+1), kk=0..3.
    short8 bfrag[8];
#pragma unroll
    for (int kk = 0; kk < 4; ++kk)
#pragma unroll
        for (int c = 0; c < 2; ++c) {
            int ct = wave * 2 + c;
            bfrag[kk * 2 + c] =
                *(const short8*)(W2s + ((((kk * 8 + ct) * 4 + q) * 16 + nn) << 3));
        }

    // ---- gather phase ----
    const int nl = threadIdx.x >> 4;            // node-local 0..15
    const int n  = blockIdx.x * 16 + nl;
    const int j  = (threadIdx.x & 15) * 8;      // 8 dims per thread
    const bool valid = n < N;

    float a[8];
#pragma unroll
    for (int k = 0; k < 8; ++k) a[k] = 0.f;

    if (valid) {
        float dv = dis[n];
        uint4 sv = *(const uint4*)(Y1 + (size_t)n * EMB + j);
        acc_fma8(sv, dv, a);                    // self term

        int e = R[n];
        const int re = R[n + 1];
        for (; e + 3 < re; e += 4) {
            int s0 = adj[e], s1 = adj[e + 1], s2 = adj[e + 2], s3 = adj[e + 3];
            float d0 = dis[s0], d1 = dis[s1], d2 = dis[s2], d3 = dis[s3];
            uint4 v0 = *(const uint4*)(Y1 + (size_t)s0 * EMB + j);
            uint4 v1 = *(const uint4*)(Y1 + (size_t)s1 * EMB + j);
            uint4 v2 = *(const uint4*)(Y1 + (size_t)s2 * EMB + j);
            uint4 v3 = *(const uint4*)(Y1 + (size_t)s3 * EMB + j);
            acc_fma8(v0, d0, a); acc_fma8(v1, d1, a);
            acc_fma8(v2, d2, a); acc_fma8(v3, d3, a);
        }
        for (; e < re; ++e) {
            int s0 = adj[e];
            uint4 v0 = *(const uint4*)(Y1 + (size_t)s0 * EMB + j);
            acc_fma8(v0, dis[s0], a);
        }

        float4 bb0 = *(const float4*)(b1 + j);
        float4 bb1 = *(const float4*)(b1 + j + 4);
        a[0] = fmaxf(dv * a[0] + bb0.x, 0.f);
        a[1] = fmaxf(dv * a[1] + bb0.y, 0.f);
        a[2] = fmaxf(dv * a[2] + bb0.z, 0.f);
        a[3] = fmaxf(dv * a[3] + bb0.w, 0.f);
        a[4] = fmaxf(dv * a[4] + bb1.x, 0.f);
        a[5] = fmaxf(dv * a[5] + bb1.y, 0.f);
        a[6] = fmaxf(dv * a[6] + bb1.z, 0.f);
        a[7] = fmaxf(dv * a[7] + bb1.w, 0.f);
    }

    // pack H row to LDS (invalid rows = zeros)
    {
        uint4 pk;
        pk.x = (unsigned)f2bf(a[0]) | ((unsigned)f2bf(a[1]) << 16);
        pk.y = (unsigned)f2bf(a[2]) | ((unsigned)f2bf(a[3]) << 16);
        pk.z = (unsigned)f2bf(a[4]) | ((unsigned)f2bf(a[5]) << 16);
        pk.w = (unsigned)f2bf(a[6]) | ((unsigned)f2bf(a[7]) << 16);
        *(uint4*)(&Hs[nl][j]) = pk;
    }
    __syncthreads();

    // ---- MFMA phase: 16x128 H  @  128x128 W2 ----
    f32x4 acc0 = (f32x4){0.f, 0.f, 0.f, 0.f};
    f32x4 acc1 = (f32x4){0.f, 0.f, 0.f, 0.f};
#pragma unroll
    for (int kk = 0; kk < 4; ++kk) {
        short8 af = *(const short8*)(&Hs[nn][kk * 32 + q * 8]);
        acc0 = __builtin_amdgcn_mfma_f32_16x16x32_bf16(af, bfrag[kk * 2 + 0], acc0, 0, 0, 0);
        acc1 = __builtin_amdgcn_mfma_f32_16x16x32_bf16(af, bfrag[kk * 2 + 1], acc1, 0, 0, 0);
    }
    __syncthreads();   // A-frag reads done block-wide before restage

    // dis-scale rows, restage for coalesced store.  D map: row m=q*4+r, col nn.
    const int ct0 = wave * 2, ct1 = wave * 2 + 1;
#pragma unroll
    for (int r = 0; r < 4; ++r) {
        int m = q * 4 + r;
        int gm = blockIdx.x * 16 + m;
        float dm = dis[gm < N ? gm : N - 1];
        Hs[m][ct0 * 16 + nn] = f2bf(acc0[r] * dm);
        Hs[m][ct1 * 16 + nn] = f2bf(acc1[r] * dm);
    }
    __syncthreads();

    // coalesced store: 16 rows x 256B = 4KB, 16B per thread
    {
        int row = threadIdx.x >> 4, off = threadIdx.x & 15;
        int gr = blockIdx.x * 16 + row;
        if (gr < N) {
            uint4 v = *(const uint4*)(&Hs[row][off * 8]);
            *((uint4*)(Y2 + (size_t)gr * EMB) + off) = v;
        }
    }
}

// ---------------- layer-2 gather: out = dis[n]*(sum + self) + b2 (f32) ----------------
// Y2 rows are pre-scaled by dis[src] in k_gather_gemm -> plain adds.
// 16 threads/node x uint4.
__global__ __launch_bounds__(256) void k_gather_out(
    const int* __restrict__ R, const int* __restrict__ adj,
    const unsigned short* __restrict__ Y, const float* __restrict__ dis,
    const float* __restrict__ bias, float* __restrict__ out, int N)
{
    int t = blockIdx.x * 256 + threadIdx.x;
    int n = t >> 4;
    if (n >= N) return;
    int j = (t & 15) * 8;

    float a[8];
#pragma unroll
    for (int k = 0; k < 8; ++k) a[k] = 0.f;

    uint4 sv = *(const uint4*)(Y + (size_t)n * EMB + j);
    acc_add8(sv, a);

    int e = R[n];
    const int re = R[n + 1];
    for (; e + 3 < re; e += 4) {
        int s0 = adj[e], s1 = adj[e + 1], s2 = adj[e + 2], s3 = adj[e + 3];
        uint4 v0 = *(const uint4*)(Y + (size_t)s0 * EMB + j);
        uint4 v1 = *(const uint4*)(Y + (size_t)s1 * EMB + j);
        uint4 v2 = *(const uint4*)(Y + (size_t)s2 * EMB + j);
        uint4 v3 = *(const uint4*)(Y + (size_t)s3 * EMB + j);
        acc_add8(v0, a); acc_add8(v1, a); acc_add8(v2, a); acc_add8(v3, a);
    }
    for (; e < re; ++e) {
        uint4 v0 = *(const uint4*)(Y + (size_t)adj[e] * EMB + j);
        acc_add8(v0, a);
    }

    const float dv = dis[n];
    float4 bb0 = *(const float4*)(bias + j);
    float4 bb1 = *(const float4*)(bias + j + 4);
    float4 o0 = { dv * a[0] + bb0.x, dv * a[1] + bb0.y,
                  dv * a[2] + bb0.z, dv * a[3] + bb0.w };
    float4 o1 = { dv * a[4] + bb1.x, dv * a[5] + bb1.y,
                  dv * a[6] + bb1.z, dv * a[7] + bb1.w };
    float* op = out + (size_t)n * EMB + j;
    *(float4*)op = o0;
    *(float4*)(op + 4) = o1;
}

extern "C" void kernel_launch(void* const* d_in, const int* in_sizes, int n_in,
                              void* d_out, int out_size, void* d_ws, size_t ws_size,
                              hipStream_t stream) {
    const int* ei = (const int*)d_in[0];
    const int E = in_sizes[0] / 2;
    const float* emb = (const float*)d_in[2];
    const int N = in_sizes[2] / EMB;
    const float* W1 = (const float*)d_in[3];
    const float* b1 = (const float*)d_in[4];
    const float* W2 = (const float*)d_in[5];
    const float* b2 = (const float*)d_in[6];
    float* out = (float*)d_out;

    const int* src = ei;
    const int* dstp = ei + E;

    // ws: dis | R | base | tot | gcnt | adj | W1s | W2s | Y2b (part overlays Y2b;
    // dead before k_gather_gemm writes it).  Y1b lives in d_out bytes (dead
    // before k_gather_out writes d_out f32).
    char* w = (char*)d_ws;
    auto take = [&](size_t bytes) { char* p = w; w += (bytes + 511) & ~(size_t)511; return p; };
    float* dis  = (float*)take((size_t)N * 4);
    int*   R    = (int*)  take((size_t)(N + 1) * 4);
    int*   base = (int*)  take((size_t)(NBUC + 1) * 4);
    int*   tot  = (int*)  take((size_t)NBUC * 4);
    int*   gcnt = (int*)  take((size_t)NBUC * 4);
    int*   adj  = (int*)  take((size_t)E * 4);
    unsigned short* W1s = (unsigned short*)take((size_t)EMB * EMB * 2);
    unsigned short* W2s = (unsigned short*)take((size_t)EMB * EMB * 2);
    unsigned short* Y2b = (unsigned short*)take((size_t)N * EMB * 2);
    int*   part = (int*)Y2b;                                 // overlay (dead before Y2b)
    unsigned short* Y1b = (unsigned short*)d_out;            // overlay in d_out

    const int NB = (N + 127) / 128;
    const int chunk = (E + NPART - 1) / NPART;
    const int gM = (N + 63) / 64;            // MFMA gemm blocks (layer 1)
    const int gF = (N + 15) / 16;            // fused gather+gemm blocks (16 nodes each)
    const int gG = (N * 16 + 255) / 256;     // layer-2 gather blocks

    // --- stage 0: zero bucket totals ---
    hipMemsetAsync(tot, 0, (size_t)NBUC * 4, stream);

    // --- K1: edge histogram -> tot, in parallel with weight pre-swizzle ---
    k_start<<<NPART + PREPB, 256, 0, stream>>>(dstp, tot, E, chunk, W1, W2, W1s, W2s);

    // --- K2: scan totals -> base, init cursors gcnt ---
    p_scan<<<1, NBUC, 0, stream>>>(tot, base, gcnt, E);

    // --- K3: reservation scatter in parallel with layer-1 GEMM (unscaled Y1b) ---
    k_mid<<<NPART + gM, 256, 0, stream>>>(src, dstp, gcnt, part, E, chunk,
                                          emb, W1s, Y1b, N);

    // --- K4: bucket -> CSR (R, adj, dis) ---
    p3_csr<<<NB, 256, 0, stream>>>(part, base, R, adj, dis, N, E);

    // --- K5: FUSED gather1 + relu + gemm2 -> Y2b = dis * (H @ W2), bf16 ---
    k_gather_gemm<<<gF, 256, 0, stream>>>(R, adj, Y1b, dis, b1, W2s, Y2b, N);

    // --- K6: layer-2 gather -> out = dis*(sum + self) + b2, f32 ---
    k_gather_out<<<gG, 256, 0, stream>>>(R, adj, Y2b, dis, b2, out, N);
}